// Round 19
// baseline (308.890 us; speedup 1.0000x reference)
//
#include <hip/hip_runtime.h>

typedef _Float16 v8h __attribute__((ext_vector_type(8)));
typedef _Float16 v4h __attribute__((ext_vector_type(4)));
typedef float v4f __attribute__((ext_vector_type(4)));
#define HF _Float16

// dims
#define Bn 8
#define Cc 512
#define CI 256
#define HW 4096   // 64*64
#define Mp 1024   // 32*32 pooled

__device__ __forceinline__ void gload16(const void* g, void* l) {
    __builtin_amdgcn_global_load_lds((const __attribute__((address_space(1))) void*)g,
                                     (__attribute__((address_space(3))) void*)l, 16, 0, 0);
}

// ---------------- prep: weights fp32->f16, BN fold ----------------
__global__ __launch_bounds__(256) void prep_kernel(
    const float* __restrict__ w_g, const float* __restrict__ b_g,
    const float* __restrict__ w_th, const float* __restrict__ b_th,
    const float* __restrict__ w_ph, const float* __restrict__ b_ph,
    const float* __restrict__ w_out, const float* __restrict__ b_out,
    const float* __restrict__ gamma, const float* __restrict__ beta,
    const float* __restrict__ mean, const float* __restrict__ var,
    HF* __restrict__ wall, float* __restrict__ ball,
    HF* __restrict__ wo, float* __restrict__ scale, float* __restrict__ shift)
{
    int idx = blockIdx.x * 256 + threadIdx.x;
    if (idx < 768*512) {
        int o = idx >> 9;
        float v = (o < 256) ? w_th[idx] : (o < 512) ? w_ph[idx - 256*512] : w_g[idx - 512*512];
        wall[idx] = (HF)v;
    }
    if (idx < 512*256) wo[idx] = (HF)w_out[idx];
    if (idx < 768) ball[idx] = (idx < 256) ? b_th[idx] : (idx < 512) ? b_ph[idx-256] : b_g[idx-512];
    if (idx < 512) {
        float inv = gamma[idx] * rsqrtf(var[idx] + 1e-5f);
        scale[idx] = inv;
        shift[idx] = (b_out[idx] - mean[idx]) * inv + beta[idx];
    }
}

// ---------------- transpose x: (b,c,s) fp32 -> xT (b,s,c) f16 ----------------
__global__ __launch_bounds__(256) void transpose_x_kernel(const float* __restrict__ x, HF* __restrict__ xT)
{
    __shared__ float tile[64][65];
    int b = blockIdx.z;
    int c0 = blockIdx.y * 64, s0 = blockIdx.x * 64;
    int tr = threadIdx.x >> 6, ts = threadIdx.x & 63;
    #pragma unroll
    for (int i = 0; i < 16; ++i) {
        int r = tr + i*4;
        tile[r][ts] = x[((long)(b*Cc) + c0 + r)*HW + s0 + ts];
    }
    __syncthreads();
    #pragma unroll
    for (int i = 0; i < 16; ++i) {
        int r = tr + i*4;
        xT[((long)b*HW + s0 + r)*Cc + c0 + ts] = (HF)tile[ts][r];
    }
}

// ---------------- gemm_bt with fused pool epilogues ----------------
// C[i,j] = sum_k A[i,k]*B[j,k]. reg-staged, padded LDS, 2 barriers/step.
// EPI 3 (TP):  theta cols (j0<256) -> C f16 = acc + colBias[j] to Cv.
//              phi cols (j0>=256) -> pool rows (s) 2x2 -> aux = Pt[m][c].
// EPI 4 (Gg):  pool cols (s) 2x2 -> Cv = G[c][m] ONLY (Gg never materialized).
template<int EPI>
__global__ __launch_bounds__(256) void gemm_bt_kernel(
    const HF* __restrict__ A, long sA, const HF* __restrict__ B, long sB,
    void* __restrict__ Cv, long sC, int M, int N, int K,
    const float* __restrict__ bias, HF* __restrict__ aux)
{
    __shared__ union USm {
        struct { alignas(16) HF As[128][40]; alignas(16) HF Bs[128][40]; } s;
        alignas(16) HF Ct[128][132];   // epilogue pool buffer (As/Bs dead)
    } u;
    int b = blockIdx.z;
    int i0 = blockIdx.y * 128;
    int j0 = blockIdx.x * 128;
    const HF* Ab = A + (long)b * sA;
    const HF* Bb = B + (long)b * sB;
    int tid = threadIdx.x;
    int lane = tid & 63, w = tid >> 6;
    int wr = w >> 1, wc = w & 1;
    int lr = lane & 15, lk = (lane >> 4) * 8;

    v4f acc[4][4];
    #pragma unroll
    for (int i = 0; i < 4; ++i)
        #pragma unroll
        for (int j = 0; j < 4; ++j) { v4f z = {0.f,0.f,0.f,0.f}; acc[i][j] = z; }

    for (int k0 = 0; k0 < K; k0 += 32) {
        #pragma unroll
        for (int q = 0; q < 2; ++q) {
            int ch = tid*2 + q;          // 0..511
            int row = ch >> 2;
            int c8 = (ch & 3) * 8;
            const uint4* ga = (const uint4*)(Ab + (long)(i0+row)*K + k0 + c8);
            *(uint4*)(&u.s.As[row][c8]) = *ga;
            const uint4* gb = (const uint4*)(Bb + (long)(j0+row)*K + k0 + c8);
            *(uint4*)(&u.s.Bs[row][c8]) = *gb;
        }
        __syncthreads();
        v8h af[4], bfr[4];
        #pragma unroll
        for (int mf = 0; mf < 4; ++mf)
            af[mf] = *(const v8h*)(&u.s.As[wr*64 + mf*16 + lr][lk]);
        #pragma unroll
        for (int nf = 0; nf < 4; ++nf)
            bfr[nf] = *(const v8h*)(&u.s.Bs[wc*64 + nf*16 + lr][lk]);
        #pragma unroll
        for (int mf = 0; mf < 4; ++mf)
            #pragma unroll
            for (int nf = 0; nf < 4; ++nf)
                acc[mf][nf] = __builtin_amdgcn_mfma_f32_16x16x32_f16(af[mf], bfr[nf], acc[mf][nf], 0, 0, 0);
        __syncthreads();
    }

    int rbase = (lane >> 4) * 4;
    bool pooled = (EPI == 4) || (EPI == 3 && j0 >= 256);
    #pragma unroll
    for (int mf = 0; mf < 4; ++mf) {
        #pragma unroll
        for (int nf = 0; nf < 4; ++nf) {
            #pragma unroll
            for (int r = 0; r < 4; ++r) {
                int rloc = wr*64 + mf*16 + rbase + r;
                int cloc = wc*64 + nf*16 + lr;
                float v = acc[mf][nf][r];
                if (EPI == 3) v += bias[j0 + cloc];        // colBias (o)
                else          v += bias[i0 + rloc];        // rowBias (c)
                if (pooled) {
                    u.Ct[rloc][cloc] = (HF)v;
                } else {  // EPI==3 theta: direct write
                    ((HF*)Cv + (long)b*sC)[(long)(i0 + rloc)*N + j0 + cloc] = (HF)v;
                }
            }
        }
    }

    if (pooled) {
        __syncthreads();
        if (EPI == 3) {
            // pool over ROWS (s): m, rows {2m,2m+1,64+2m,64+2m+1} -> Pt[m0+m][j0-256 + oc]
            int m = tid >> 3, oc = (tid & 7) * 16;
            int m0 = (i0 >> 7) * 32;
            HF* Pt_ = aux + (long)b*Mp*CI;
            HF res[16];
            #pragma unroll
            for (int j = 0; j < 16; ++j) {
                float v0 = fmaxf((float)u.Ct[2*m][oc+j],    (float)u.Ct[2*m+1][oc+j]);
                float v1 = fmaxf((float)u.Ct[64+2*m][oc+j], (float)u.Ct[64+2*m+1][oc+j]);
                res[j] = (HF)fmaxf(v0, v1);
            }
            HF* dst = Pt_ + (long)(m0 + m)*CI + (j0 - 256) + oc;
            *(v8h*)dst = *(v8h*)&res[0];
            *(v8h*)(dst + 8) = *(v8h*)&res[8];
        } else {
            // pool over COLS (s): G[i0+c][m0 + mg..mg+15]
            int c = tid >> 1, mg = (tid & 1) * 16;
            int m0 = (j0 >> 7) * 32;
            HF* Gp = (HF*)Cv + (long)b*sC;
            HF res[16];
            #pragma unroll
            for (int j = 0; j < 16; ++j) {
                int mm = mg + j;
                float v0 = fmaxf((float)u.Ct[c][2*mm],    (float)u.Ct[c][2*mm+1]);
                float v1 = fmaxf((float)u.Ct[c][64+2*mm], (float)u.Ct[c][64+2*mm+1]);
                res[j] = (HF)fmaxf(v0, v1);
            }
            HF* dst = Gp + (long)(i0 + c)*Mp + m0 + mg;
            *(v8h*)dst = *(v8h*)&res[0];
            *(v8h*)(dst + 8) = *(v8h*)&res[8];
        }
    }
}

// ---------------- fused flash attention v15: 32-row tiles, 1024 blocks, 4 blocks/CU ----
// 1024 blocks x 256 thr (4 waves). batch = bid&7 (XCD-pinned). 16 waves/CU (2x TLP).
// Waves 0-1: swapped QK^T + softmax (16 rows each). ALL waves: c-split PV (64 cols
// each) + fused out-conv epilogue. P staged via gload_lds double-buffer (shared by
// all 4 waves); G regs from L2 1 iter ahead; defer-rescale THR=7.
// LDS ~37.6 KB (union Y over P bufs) -> 4 blocks/CU at VGPR<=128.
__global__ __launch_bounds__(256, 4) void fused_attn_kernel(
    const HF* __restrict__ TP,   // [B][4096][512], theta = cols 0..255
    const HF* __restrict__ Pt,   // [B][1024][256]
    const HF* __restrict__ G,    // [B][256][1024]
    const HF* __restrict__ wo,   // [512][256]
    const float* __restrict__ scale, const float* __restrict__ shift,
    const float* __restrict__ x, // [B][512][4096] fp32
    float* __restrict__ out)     // [B][512][4096] fp32
{
    __shared__ union SMem {
        struct {
            alignas(16) HF P_lds[2][8192];      // [32 kg][32 row][8] k-group-major
            alignas(16) HF P_buf[2][2][16][36]; // [pb][rowgrp][n 16][m 32+4pad]
            alignas(16) float smem_a[2][2][16]; // [pb][rowgrp][n] alpha
        } m;
        alignas(16) HF Y[32][264];              // epilogue: normalized Y (row 528B)
    } sm;
    __shared__ float smem_l[32];                // final row sums

    int bid = blockIdx.x;
    int b = bid & 7;
    int ntile = bid >> 3;          // 0..127
    int tid = threadIdx.x;
    int lane = tid & 63, w = tid >> 6;
    int lr = lane & 15, lkg = lane >> 4;
    int nbase = ntile * 32;

    const HF* Pb = Pt + (long)b*Mp*CI;
    const HF* Gb = G  + (long)b*CI*Mp + (long)(w*64)*Mp;     // my c-quadrant

    auto stage = [&](int bsel, int m0) {
        #pragma unroll
        for (int q = 0; q < 4; ++q) {
            int idxp = (w*4 + q)*64 + lane;         // 0..1023; dest = idxp*16B
            int pkg = idxp >> 5, prow = idxp & 31;  // [32 kg][32 row][8]
            gload16(Pb + (long)(m0 + prow)*CI + pkg*8, sm.m.P_lds[bsel] + (size_t)idxp*8);
        }
    };
    auto loadG = [&](int m0, v8h* g) {
        #pragma unroll
        for (int ct = 0; ct < 4; ++ct)
            g[ct] = *(const v8h*)(Gb + (long)(ct*16 + lr)*Mp + m0 + lkg*8);
    };

    // Q fragments (waves 0-1 only; rows nbase + w*16 + lr)
    v8h af[8];
    if (w < 2) {
        const HF* Tq = TP + ((long)b*HW + nbase + w*16) * 512;
        #pragma unroll
        for (int kf = 0; kf < 8; ++kf)
            af[kf] = *(const v8h*)(Tq + (long)lr*512 + kf*32 + lkg*8);
    }

    v4f acc_y[2][4];   // [row-tile rt][c-tile ct]; Y row = rt*16+lkg*4+r, col = w*64+ct*16+lr
    #pragma unroll
    for (int i = 0; i < 2; ++i)
        #pragma unroll
        for (int j = 0; j < 4; ++j) { v4f z = {0.f,0.f,0.f,0.f}; acc_y[i][j] = z; }
    float mrun = -1e30f;   // (waves 0-1) running max for my row n = nbase + w*16 + lr
    float lsum = 0.f;      // (waves 0-1) per-lane partial sum over my m's

    v8h gA[4], gB[4];
    stage(0, 0);
    loadG(0, gA);
    __syncthreads();

    for (int t = 0; t < 32; ++t) {
        int cur = t & 1;
        int pb = t & 1;
        v8h* gcur  = (t & 1) ? gB : gA;
        v8h* gnext = (t & 1) ? gA : gB;
        if (t < 31) {
            stage(cur ^ 1, (t+1)*32);     // gload_lds next P chunk
            loadG((t+1)*32, gnext);       // G regs next chunk (issue-early)
        }

        if (w < 2) {
            // QK^T swapped: acc[mt] holds S[n=lr][m = mt*16 + lkg*4 + r]
            v4f acc[2];
            #pragma unroll
            for (int mt = 0; mt < 2; ++mt) { v4f z = {0.f,0.f,0.f,0.f}; acc[mt] = z; }
            __builtin_amdgcn_s_setprio(1);
            #pragma unroll
            for (int kf = 0; kf < 8; ++kf) {
                #pragma unroll
                for (int mt = 0; mt < 2; ++mt) {
                    v8h pf = *(const v8h*)(sm.m.P_lds[cur] + (kf*4 + lkg)*256 + (mt*16 + lr)*8);
                    acc[mt] = __builtin_amdgcn_mfma_f32_16x16x32_f16(pf, af[kf], acc[mt], 0, 0, 0);
                }
            }
            __builtin_amdgcn_s_setprio(0);

            // softmax: per-lane row n=lr. 7 in-lane max + 2 shuffles.
            float cm = fmaxf(fmaxf(fmaxf(acc[0][0], acc[0][1]), fmaxf(acc[0][2], acc[0][3])),
                             fmaxf(fmaxf(acc[1][0], acc[1][1]), fmaxf(acc[1][2], acc[1][3])));
            cm = fmaxf(cm, __shfl_xor(cm, 16));
            cm = fmaxf(cm, __shfl_xor(cm, 32));
            float alpha = 1.f;
            if (cm > mrun + 7.f) {            // defer: p <= e^7 = 1096, f16-safe
                alpha = __expf(mrun - cm);    // first iter: exp(-inf)=0 zeroes empty acc
                mrun = cm;
                lsum *= alpha;
            }
            if (lane < 16) sm.m.smem_a[pb][w][lr] = alpha;
            #pragma unroll
            for (int mt = 0; mt < 2; ++mt) {
                v4h p4;
                #pragma unroll
                for (int r = 0; r < 4; ++r) {
                    float p = __expf(acc[mt][r] - mrun);
                    lsum += p;
                    p4[r] = (HF)p;
                }
                *(v4h*)(&sm.m.P_buf[pb][w][lr][mt*16 + lkg*4]) = p4;   // one b64 per mt
            }
        }

        __syncthreads();   // P_buf[pb]+smem_a[pb] visible; vmcnt drained

        // PV (all waves): Y[32 n][my 64 c] += P(32x32) @ G^T (G in registers)
        __builtin_amdgcn_s_setprio(1);
        v4f alv[2];
        bool need = false;
        #pragma unroll
        for (int rt = 0; rt < 2; ++rt) {
            alv[rt] = *(const v4f*)(&sm.m.smem_a[pb][rt][lkg*4]);
            need = need | (alv[rt][0] != 1.f) | (alv[rt][1] != 1.f)
                        | (alv[rt][2] != 1.f) | (alv[rt][3] != 1.f);
        }
        if (__any(need)) {
            #pragma unroll
            for (int rt = 0; rt < 2; ++rt)
                #pragma unroll
                for (int ct = 0; ct < 4; ++ct)
                    #pragma unroll
                    for (int r = 0; r < 4; ++r)
                        acc_y[rt][ct][r] *= alv[rt][r];
        }
        #pragma unroll
        for (int rt = 0; rt < 2; ++rt) {
            v8h ap;
            {
                v4h a0 = *(const v4h*)(&sm.m.P_buf[pb][rt][lr][lkg*8]);
                v4h a1 = *(const v4h*)(&sm.m.P_buf[pb][rt][lr][lkg*8 + 4]);
                ap = __builtin_shufflevector(a0, a1, 0,1,2,3,4,5,6,7);
            }
            #pragma unroll
            for (int ct = 0; ct < 4; ++ct)
                acc_y[rt][ct] = __builtin_amdgcn_mfma_f32_16x16x32_f16(ap, gcur[ct], acc_y[rt][ct], 0, 0, 0);
        }
        __builtin_amdgcn_s_setprio(0);
    }

    // ---- epilogue 1: row sums (waves 0-1), normalize Y into LDS (union overlay) ----
    if (w < 2) {
        lsum += __shfl_xor(lsum, 16);
        lsum += __shfl_xor(lsum, 32);
        if (lane < 16) smem_l[w*16 + lr] = lsum;
    }
    __syncthreads();
    #pragma unroll
    for (int rt = 0; rt < 2; ++rt) {
        #pragma unroll
        for (int r = 0; r < 4; ++r) {
            int row = rt*16 + lkg*4 + r;
            float inv = 1.f / smem_l[row];
            #pragma unroll
            for (int ct = 0; ct < 4; ++ct)
                sm.Y[row][w*64 + ct*16 + lr] = (HF)(acc_y[rt][ct][r] * inv);
        }
    }
    __syncthreads();

    // ---- epilogue 2: out[co][n] = (wo @ Y^T) * scale + shift + x, co-slab per wave ----
    const HF* wob = wo + (long)(w*128)*CI;   // my 128 co rows
    v4f acc2[8][2];
    #pragma unroll
    for (int i = 0; i < 8; ++i)
        #pragma unroll
        for (int j = 0; j < 2; ++j) { v4f z = {0.f,0.f,0.f,0.f}; acc2[i][j] = z; }
    #pragma unroll
    for (int kf = 0; kf < 8; ++kf) {
        v8h bf2[2];
        #pragma unroll
        for (int nt = 0; nt < 2; ++nt)
            bf2[nt] = *(const v8h*)(&sm.Y[nt*16 + lr][kf*32 + lkg*8]);
        #pragma unroll
        for (int cot = 0; cot < 8; ++cot) {
            v8h af2 = *(const v8h*)(wob + (long)(cot*16 + lr)*CI + kf*32 + lkg*8);
            #pragma unroll
            for (int nt = 0; nt < 2; ++nt)
                acc2[cot][nt] = __builtin_amdgcn_mfma_f32_16x16x32_f16(af2, bf2[nt], acc2[cot][nt], 0, 0, 0);
        }
    }
    const float* xb = x + (long)b*Cc*HW + nbase;
    float* ob = out + (long)b*Cc*HW + nbase;
    #pragma unroll
    for (int cot = 0; cot < 8; ++cot) {
        int co = w*128 + cot*16 + lkg*4;
        #pragma unroll
        for (int r = 0; r < 4; ++r) {
            float sc = scale[co + r], sh = shift[co + r];
            #pragma unroll
            for (int nt = 0; nt < 2; ++nt) {
                long o = (long)(co + r)*HW + nt*16 + lr;
                ob[o] = acc2[cot][nt][r] * sc + sh + xb[o];
            }
        }
    }
}

extern "C" void kernel_launch(void* const* d_in, const int* in_sizes, int n_in,
                              void* d_out, int out_size, void* d_ws, size_t ws_size,
                              hipStream_t stream)
{
    const float* x     = (const float*)d_in[0];
    const float* w_g   = (const float*)d_in[1];
    const float* b_g   = (const float*)d_in[2];
    const float* w_th  = (const float*)d_in[3];
    const float* b_th  = (const float*)d_in[4];
    const float* w_ph  = (const float*)d_in[5];
    const float* b_ph  = (const float*)d_in[6];
    const float* w_out = (const float*)d_in[7];
    const float* b_out = (const float*)d_in[8];
    const float* gamma = (const float*)d_in[9];
    const float* beta  = (const float*)d_in[10];
    const float* mean  = (const float*)d_in[11];
    const float* var   = (const float*)d_in[12];
    float* out = (float*)d_out;

    char* ws = (char*)d_ws;
    size_t off = 0;
    auto alloc = [&](size_t bytes) { void* p = ws + off; off += (bytes + 255) & ~(size_t)255; return p; };
    HF*    wall  = (HF*)alloc((size_t)768*512*2);   // rows: theta 0-255, phi 256-511, g 512-767
    float* ball  = (float*)alloc(768*4);
    HF*    wo    = (HF*)alloc((size_t)512*256*2);
    float* scale = (float*)alloc(512*4);
    float* shift = (float*)alloc(512*4);
    HF*    xT    = (HF*)alloc((size_t)Bn*HW*Cc*2);
    HF*    TP    = (HF*)alloc((size_t)Bn*HW*512*2);  // [s][theta|phi] (phi half unused)
    HF*    Pt    = (HF*)alloc((size_t)Bn*Mp*CI*2);
    HF*    G     = (HF*)alloc((size_t)Bn*CI*Mp*2);

    prep_kernel<<<1536, 256, 0, stream>>>(w_g,b_g,w_th,b_th,w_ph,b_ph,w_out,b_out,gamma,beta,mean,var,
                                          wall, ball, wo, scale, shift);
    transpose_x_kernel<<<dim3(64,8,Bn), 256, 0, stream>>>(x, xT);
    // TP GEMM: theta written to TP; phi pooled in-epilogue -> Pt[m][c]
    gemm_bt_kernel<3><<<dim3(4,32,Bn), 256, 0, stream>>>(xT, (long)HW*Cc, wall, 0, TP, (long)HW*512,
                                                         HW, 512, Cc, ball, Pt);
    // Gg GEMM: C never materialized; pooled in-epilogue -> G[c][m]
    gemm_bt_kernel<4><<<dim3(32,2,Bn), 256, 0, stream>>>(wall + (size_t)512*512, 0, xT, (long)HW*Cc,
                                                         G, (long)CI*Mp, CI, HW, Cc, ball + 512, nullptr);
    // fused scores+softmax+PV+outconv+BN+residual -> out
    fused_attn_kernel<<<1024, 256, 0, stream>>>(TP, Pt, G, wo, scale, shift, x, out);
}

// Round 20
// 276.798 us; speedup vs baseline: 1.1159x; 1.1159x over previous
//
#include <hip/hip_runtime.h>

typedef _Float16 v8h __attribute__((ext_vector_type(8)));
typedef _Float16 v4h __attribute__((ext_vector_type(4)));
typedef float v4f __attribute__((ext_vector_type(4)));
#define HF _Float16

// dims
#define Bn 8
#define Cc 512
#define CI 256
#define HW 4096   // 64*64
#define Mp 1024   // 32*32 pooled

__device__ __forceinline__ void gload16(const void* g, void* l) {
    __builtin_amdgcn_global_load_lds((const __attribute__((address_space(1))) void*)g,
                                     (__attribute__((address_space(3))) void*)l, 16, 0, 0);
}

// ---------------- prep: weights fp32->f16, BN fold ----------------
__global__ __launch_bounds__(256) void prep_kernel(
    const float* __restrict__ w_g, const float* __restrict__ b_g,
    const float* __restrict__ w_th, const float* __restrict__ b_th,
    const float* __restrict__ w_ph, const float* __restrict__ b_ph,
    const float* __restrict__ w_out, const float* __restrict__ b_out,
    const float* __restrict__ gamma, const float* __restrict__ beta,
    const float* __restrict__ mean, const float* __restrict__ var,
    HF* __restrict__ wall, float* __restrict__ ball,
    HF* __restrict__ wo, float* __restrict__ scale, float* __restrict__ shift)
{
    int idx = blockIdx.x * 256 + threadIdx.x;
    if (idx < 768*512) {
        int o = idx >> 9;
        float v = (o < 256) ? w_th[idx] : (o < 512) ? w_ph[idx - 256*512] : w_g[idx - 512*512];
        wall[idx] = (HF)v;
    }
    if (idx < 512*256) wo[idx] = (HF)w_out[idx];
    if (idx < 768) ball[idx] = (idx < 256) ? b_th[idx] : (idx < 512) ? b_ph[idx-256] : b_g[idx-512];
    if (idx < 512) {
        float inv = gamma[idx] * rsqrtf(var[idx] + 1e-5f);
        scale[idx] = inv;
        shift[idx] = (b_out[idx] - mean[idx]) * inv + beta[idx];
    }
}

// ---------------- transpose x: (b,c,s) fp32 -> xT (b,s,c) f16 ----------------
__global__ __launch_bounds__(256) void transpose_x_kernel(const float* __restrict__ x, HF* __restrict__ xT)
{
    __shared__ float tile[64][65];
    int b = blockIdx.z;
    int c0 = blockIdx.y * 64, s0 = blockIdx.x * 64;
    int tr = threadIdx.x >> 6, ts = threadIdx.x & 63;
    #pragma unroll
    for (int i = 0; i < 16; ++i) {
        int r = tr + i*4;
        tile[r][ts] = x[((long)(b*Cc) + c0 + r)*HW + s0 + ts];
    }
    __syncthreads();
    #pragma unroll
    for (int i = 0; i < 16; ++i) {
        int r = tr + i*4;
        xT[((long)b*HW + s0 + r)*Cc + c0 + ts] = (HF)tile[ts][r];
    }
}

// ---------------- gemm_bt with fused pool epilogues ----------------
// C[i,j] = sum_k A[i,k]*B[j,k]. reg-staged, padded LDS, 2 barriers/step.
// EPI 3 (TP):  theta cols (j0<256) -> C f16 = acc + colBias[j] to Cv.
//              phi cols (j0>=256) -> pool rows (s) 2x2 -> aux = Pt[m][c].
// EPI 4 (Gg):  pool cols (s) 2x2 -> Cv = G[c][m] ONLY (Gg never materialized).
template<int EPI>
__global__ __launch_bounds__(256) void gemm_bt_kernel(
    const HF* __restrict__ A, long sA, const HF* __restrict__ B, long sB,
    void* __restrict__ Cv, long sC, int M, int N, int K,
    const float* __restrict__ bias, HF* __restrict__ aux)
{
    __shared__ union USm {
        struct { alignas(16) HF As[128][40]; alignas(16) HF Bs[128][40]; } s;
        alignas(16) HF Ct[128][132];   // epilogue pool buffer (As/Bs dead)
    } u;
    int b = blockIdx.z;
    int i0 = blockIdx.y * 128;
    int j0 = blockIdx.x * 128;
    const HF* Ab = A + (long)b * sA;
    const HF* Bb = B + (long)b * sB;
    int tid = threadIdx.x;
    int lane = tid & 63, w = tid >> 6;
    int wr = w >> 1, wc = w & 1;
    int lr = lane & 15, lk = (lane >> 4) * 8;

    v4f acc[4][4];
    #pragma unroll
    for (int i = 0; i < 4; ++i)
        #pragma unroll
        for (int j = 0; j < 4; ++j) { v4f z = {0.f,0.f,0.f,0.f}; acc[i][j] = z; }

    for (int k0 = 0; k0 < K; k0 += 32) {
        #pragma unroll
        for (int q = 0; q < 2; ++q) {
            int ch = tid*2 + q;          // 0..511
            int row = ch >> 2;
            int c8 = (ch & 3) * 8;
            const uint4* ga = (const uint4*)(Ab + (long)(i0+row)*K + k0 + c8);
            *(uint4*)(&u.s.As[row][c8]) = *ga;
            const uint4* gb = (const uint4*)(Bb + (long)(j0+row)*K + k0 + c8);
            *(uint4*)(&u.s.Bs[row][c8]) = *gb;
        }
        __syncthreads();
        v8h af[4], bfr[4];
        #pragma unroll
        for (int mf = 0; mf < 4; ++mf)
            af[mf] = *(const v8h*)(&u.s.As[wr*64 + mf*16 + lr][lk]);
        #pragma unroll
        for (int nf = 0; nf < 4; ++nf)
            bfr[nf] = *(const v8h*)(&u.s.Bs[wc*64 + nf*16 + lr][lk]);
        #pragma unroll
        for (int mf = 0; mf < 4; ++mf)
            #pragma unroll
            for (int nf = 0; nf < 4; ++nf)
                acc[mf][nf] = __builtin_amdgcn_mfma_f32_16x16x32_f16(af[mf], bfr[nf], acc[mf][nf], 0, 0, 0);
        __syncthreads();
    }

    int rbase = (lane >> 4) * 4;
    bool pooled = (EPI == 4) || (EPI == 3 && j0 >= 256);
    #pragma unroll
    for (int mf = 0; mf < 4; ++mf) {
        #pragma unroll
        for (int nf = 0; nf < 4; ++nf) {
            #pragma unroll
            for (int r = 0; r < 4; ++r) {
                int rloc = wr*64 + mf*16 + rbase + r;
                int cloc = wc*64 + nf*16 + lr;
                float v = acc[mf][nf][r];
                if (EPI == 3) v += bias[j0 + cloc];        // colBias (o)
                else          v += bias[i0 + rloc];        // rowBias (c)
                if (pooled) {
                    u.Ct[rloc][cloc] = (HF)v;
                } else {  // EPI==3 theta: direct write
                    ((HF*)Cv + (long)b*sC)[(long)(i0 + rloc)*N + j0 + cloc] = (HF)v;
                }
            }
        }
    }

    if (pooled) {
        __syncthreads();
        if (EPI == 3) {
            // pool over ROWS (s): rows {2m,2m+1,64+2m,64+2m+1} -> Pt[m0+m][j0-256 + oc]
            int m = tid >> 3, oc = (tid & 7) * 16;
            int m0 = (i0 >> 7) * 32;
            HF* Pt_ = aux + (long)b*Mp*CI;
            HF res[16];
            #pragma unroll
            for (int j = 0; j < 16; ++j) {
                float v0 = fmaxf((float)u.Ct[2*m][oc+j],    (float)u.Ct[2*m+1][oc+j]);
                float v1 = fmaxf((float)u.Ct[64+2*m][oc+j], (float)u.Ct[64+2*m+1][oc+j]);
                res[j] = (HF)fmaxf(v0, v1);
            }
            HF* dst = Pt_ + (long)(m0 + m)*CI + (j0 - 256) + oc;
            *(v8h*)dst = *(v8h*)&res[0];
            *(v8h*)(dst + 8) = *(v8h*)&res[8];
        } else {
            // pool over COLS (s): G[i0+c][m0 + mg..mg+15]
            int c = tid >> 1, mg = (tid & 1) * 16;
            int m0 = (j0 >> 7) * 32;
            HF* Gp = (HF*)Cv + (long)b*sC;
            HF res[16];
            #pragma unroll
            for (int j = 0; j < 16; ++j) {
                int mm = mg + j;
                float v0 = fmaxf((float)u.Ct[c][2*mm],    (float)u.Ct[c][2*mm+1]);
                float v1 = fmaxf((float)u.Ct[c][64+2*mm], (float)u.Ct[c][64+2*mm+1]);
                res[j] = (HF)fmaxf(v0, v1);
            }
            HF* dst = Gp + (long)(i0 + c)*Mp + m0 + mg;
            *(v8h*)dst = *(v8h*)&res[0];
            *(v8h*)(dst + 8) = *(v8h*)&res[8];
        }
    }
}

// ---------------- fused flash attention v16: 32-row tiles, 1024 blocks ----------------
// Same as r19 v15 but __launch_bounds__(256, 2): no forced VGPR cap (r19's (256,4)
// capped at 64 VGPR -> massive scratch spill, WRITE 117MB). Natural VGPR ~96-112
// <= 128 => HW grants 4 waves/SIMD = 4 blocks/CU (LDS 37.9KB x 4 fits 160KB).
// Waves 0-1: swapped QK^T + softmax (16 rows each). ALL waves: c-split PV + fused
// out-conv epilogue. batch = bid&7 (XCD-pinned).
__global__ __launch_bounds__(256, 2) void fused_attn_kernel(
    const HF* __restrict__ TP,   // [B][4096][512], theta = cols 0..255
    const HF* __restrict__ Pt,   // [B][1024][256]
    const HF* __restrict__ G,    // [B][256][1024]
    const HF* __restrict__ wo,   // [512][256]
    const float* __restrict__ scale, const float* __restrict__ shift,
    const float* __restrict__ x, // [B][512][4096] fp32
    float* __restrict__ out)     // [B][512][4096] fp32
{
    __shared__ union SMem {
        struct {
            alignas(16) HF P_lds[2][8192];      // [32 kg][32 row][8] k-group-major
            alignas(16) HF P_buf[2][2][16][36]; // [pb][rowgrp][n 16][m 32+4pad]
            alignas(16) float smem_a[2][2][16]; // [pb][rowgrp][n] alpha
        } m;
        alignas(16) HF Y[32][264];              // epilogue: normalized Y (row 528B)
    } sm;
    __shared__ float smem_l[32];                // final row sums

    int bid = blockIdx.x;
    int b = bid & 7;
    int ntile = bid >> 3;          // 0..127
    int tid = threadIdx.x;
    int lane = tid & 63, w = tid >> 6;
    int lr = lane & 15, lkg = lane >> 4;
    int nbase = ntile * 32;

    const HF* Pb = Pt + (long)b*Mp*CI;
    const HF* Gb = G  + (long)b*CI*Mp + (long)(w*64)*Mp;     // my c-quadrant

    auto stage = [&](int bsel, int m0) {
        #pragma unroll
        for (int q = 0; q < 4; ++q) {
            int idxp = (w*4 + q)*64 + lane;         // 0..1023; dest = idxp*16B
            int pkg = idxp >> 5, prow = idxp & 31;  // [32 kg][32 row][8]
            gload16(Pb + (long)(m0 + prow)*CI + pkg*8, sm.m.P_lds[bsel] + (size_t)idxp*8);
        }
    };
    auto loadG = [&](int m0, v8h* g) {
        #pragma unroll
        for (int ct = 0; ct < 4; ++ct)
            g[ct] = *(const v8h*)(Gb + (long)(ct*16 + lr)*Mp + m0 + lkg*8);
    };

    // Q fragments (waves 0-1 only; rows nbase + w*16 + lr)
    v8h af[8];
    if (w < 2) {
        const HF* Tq = TP + ((long)b*HW + nbase + w*16) * 512;
        #pragma unroll
        for (int kf = 0; kf < 8; ++kf)
            af[kf] = *(const v8h*)(Tq + (long)lr*512 + kf*32 + lkg*8);
    }

    v4f acc_y[2][4];   // [row-tile rt][c-tile ct]; Y row = rt*16+lkg*4+r, col = w*64+ct*16+lr
    #pragma unroll
    for (int i = 0; i < 2; ++i)
        #pragma unroll
        for (int j = 0; j < 4; ++j) { v4f z = {0.f,0.f,0.f,0.f}; acc_y[i][j] = z; }
    float mrun = -1e30f;   // (waves 0-1) running max for my row n = nbase + w*16 + lr
    float lsum = 0.f;      // (waves 0-1) per-lane partial sum over my m's

    v8h gA[4], gB[4];
    stage(0, 0);
    loadG(0, gA);
    __syncthreads();

    for (int t = 0; t < 32; ++t) {
        int cur = t & 1;
        int pb = t & 1;
        v8h* gcur  = (t & 1) ? gB : gA;
        v8h* gnext = (t & 1) ? gA : gB;
        if (t < 31) {
            stage(cur ^ 1, (t+1)*32);     // gload_lds next P chunk
            loadG((t+1)*32, gnext);       // G regs next chunk (issue-early)
        }

        if (w < 2) {
            // QK^T swapped: acc[mt] holds S[n=lr][m = mt*16 + lkg*4 + r]
            v4f acc[2];
            #pragma unroll
            for (int mt = 0; mt < 2; ++mt) { v4f z = {0.f,0.f,0.f,0.f}; acc[mt] = z; }
            __builtin_amdgcn_s_setprio(1);
            #pragma unroll
            for (int kf = 0; kf < 8; ++kf) {
                #pragma unroll
                for (int mt = 0; mt < 2; ++mt) {
                    v8h pf = *(const v8h*)(sm.m.P_lds[cur] + (kf*4 + lkg)*256 + (mt*16 + lr)*8);
                    acc[mt] = __builtin_amdgcn_mfma_f32_16x16x32_f16(pf, af[kf], acc[mt], 0, 0, 0);
                }
            }
            __builtin_amdgcn_s_setprio(0);

            // softmax: per-lane row n=lr. 7 in-lane max + 2 shuffles.
            float cm = fmaxf(fmaxf(fmaxf(acc[0][0], acc[0][1]), fmaxf(acc[0][2], acc[0][3])),
                             fmaxf(fmaxf(acc[1][0], acc[1][1]), fmaxf(acc[1][2], acc[1][3])));
            cm = fmaxf(cm, __shfl_xor(cm, 16));
            cm = fmaxf(cm, __shfl_xor(cm, 32));
            float alpha = 1.f;
            if (cm > mrun + 7.f) {            // defer: p <= e^7 = 1096, f16-safe
                alpha = __expf(mrun - cm);    // first iter: exp(-inf)=0 zeroes empty acc
                mrun = cm;
                lsum *= alpha;
            }
            if (lane < 16) sm.m.smem_a[pb][w][lr] = alpha;
            #pragma unroll
            for (int mt = 0; mt < 2; ++mt) {
                v4h p4;
                #pragma unroll
                for (int r = 0; r < 4; ++r) {
                    float p = __expf(acc[mt][r] - mrun);
                    lsum += p;
                    p4[r] = (HF)p;
                }
                *(v4h*)(&sm.m.P_buf[pb][w][lr][mt*16 + lkg*4]) = p4;   // one b64 per mt
            }
        }

        __syncthreads();   // P_buf[pb]+smem_a[pb] visible; vmcnt drained

        // PV (all waves): Y[32 n][my 64 c] += P(32x32) @ G^T (G in registers)
        __builtin_amdgcn_s_setprio(1);
        v4f alv[2];
        bool need = false;
        #pragma unroll
        for (int rt = 0; rt < 2; ++rt) {
            alv[rt] = *(const v4f*)(&sm.m.smem_a[pb][rt][lkg*4]);
            need = need | (alv[rt][0] != 1.f) | (alv[rt][1] != 1.f)
                        | (alv[rt][2] != 1.f) | (alv[rt][3] != 1.f);
        }
        if (__any(need)) {
            #pragma unroll
            for (int rt = 0; rt < 2; ++rt)
                #pragma unroll
                for (int ct = 0; ct < 4; ++ct)
                    #pragma unroll
                    for (int r = 0; r < 4; ++r)
                        acc_y[rt][ct][r] *= alv[rt][r];
        }
        #pragma unroll
        for (int rt = 0; rt < 2; ++rt) {
            v8h ap;
            {
                v4h a0 = *(const v4h*)(&sm.m.P_buf[pb][rt][lr][lkg*8]);
                v4h a1 = *(const v4h*)(&sm.m.P_buf[pb][rt][lr][lkg*8 + 4]);
                ap = __builtin_shufflevector(a0, a1, 0,1,2,3,4,5,6,7);
            }
            #pragma unroll
            for (int ct = 0; ct < 4; ++ct)
                acc_y[rt][ct] = __builtin_amdgcn_mfma_f32_16x16x32_f16(ap, gcur[ct], acc_y[rt][ct], 0, 0, 0);
        }
        __builtin_amdgcn_s_setprio(0);
    }

    // ---- epilogue 1: row sums (waves 0-1), normalize Y into LDS (union overlay) ----
    if (w < 2) {
        lsum += __shfl_xor(lsum, 16);
        lsum += __shfl_xor(lsum, 32);
        if (lane < 16) smem_l[w*16 + lr] = lsum;
    }
    __syncthreads();
    #pragma unroll
    for (int rt = 0; rt < 2; ++rt) {
        #pragma unroll
        for (int r = 0; r < 4; ++r) {
            int row = rt*16 + lkg*4 + r;
            float inv = 1.f / smem_l[row];
            #pragma unroll
            for (int ct = 0; ct < 4; ++ct)
                sm.Y[row][w*64 + ct*16 + lr] = (HF)(acc_y[rt][ct][r] * inv);
        }
    }
    __syncthreads();

    // ---- epilogue 2: out[co][n] = (wo @ Y^T) * scale + shift + x, co-slab per wave ----
    const HF* wob = wo + (long)(w*128)*CI;   // my 128 co rows
    v4f acc2[8][2];
    #pragma unroll
    for (int i = 0; i < 8; ++i)
        #pragma unroll
        for (int j = 0; j < 2; ++j) { v4f z = {0.f,0.f,0.f,0.f}; acc2[i][j] = z; }
    #pragma unroll
    for (int kf = 0; kf < 8; ++kf) {
        v8h bf2[2];
        #pragma unroll
        for (int nt = 0; nt < 2; ++nt)
            bf2[nt] = *(const v8h*)(&sm.Y[nt*16 + lr][kf*32 + lkg*8]);
        #pragma unroll
        for (int cot = 0; cot < 8; ++cot) {
            v8h af2 = *(const v8h*)(wob + (long)(cot*16 + lr)*CI + kf*32 + lkg*8);
            #pragma unroll
            for (int nt = 0; nt < 2; ++nt)
                acc2[cot][nt] = __builtin_amdgcn_mfma_f32_16x16x32_f16(af2, bf2[nt], acc2[cot][nt], 0, 0, 0);
        }
    }
    const float* xb = x + (long)b*Cc*HW + nbase;
    float* ob = out + (long)b*Cc*HW + nbase;
    #pragma unroll
    for (int cot = 0; cot < 8; ++cot) {
        int co = w*128 + cot*16 + lkg*4;
        #pragma unroll
        for (int r = 0; r < 4; ++r) {
            float sc = scale[co + r], sh = shift[co + r];
            #pragma unroll
            for (int nt = 0; nt < 2; ++nt) {
                long o = (long)(co + r)*HW + nt*16 + lr;
                ob[o] = acc2[cot][nt][r] * sc + sh + xb[o];
            }
        }
    }
}

extern "C" void kernel_launch(void* const* d_in, const int* in_sizes, int n_in,
                              void* d_out, int out_size, void* d_ws, size_t ws_size,
                              hipStream_t stream)
{
    const float* x     = (const float*)d_in[0];
    const float* w_g   = (const float*)d_in[1];
    const float* b_g   = (const float*)d_in[2];
    const float* w_th  = (const float*)d_in[3];
    const float* b_th  = (const float*)d_in[4];
    const float* w_ph  = (const float*)d_in[5];
    const float* b_ph  = (const float*)d_in[6];
    const float* w_out = (const float*)d_in[7];
    const float* b_out = (const float*)d_in[8];
    const float* gamma = (const float*)d_in[9];
    const float* beta  = (const float*)d_in[10];
    const float* mean  = (const float*)d_in[11];
    const float* var   = (const float*)d_in[12];
    float* out = (float*)d_out;

    char* ws = (char*)d_ws;
    size_t off = 0;
    auto alloc = [&](size_t bytes) { void* p = ws + off; off += (bytes + 255) & ~(size_t)255; return p; };
    HF*    wall  = (HF*)alloc((size_t)768*512*2);   // rows: theta 0-255, phi 256-511, g 512-767
    float* ball  = (float*)alloc(768*4);
    HF*    wo    = (HF*)alloc((size_t)512*256*2);
    float* scale = (float*)alloc(512*4);
    float* shift = (float*)alloc(512*4);
    HF*    xT    = (HF*)alloc((size_t)Bn*HW*Cc*2);
    HF*    TP    = (HF*)alloc((size_t)Bn*HW*512*2);  // [s][theta|phi] (phi half unused)
    HF*    Pt    = (HF*)alloc((size_t)Bn*Mp*CI*2);
    HF*    G     = (HF*)alloc((size_t)Bn*CI*Mp*2);

    prep_kernel<<<1536, 256, 0, stream>>>(w_g,b_g,w_th,b_th,w_ph,b_ph,w_out,b_out,gamma,beta,mean,var,
                                          wall, ball, wo, scale, shift);
    transpose_x_kernel<<<dim3(64,8,Bn), 256, 0, stream>>>(x, xT);
    // TP GEMM: theta written to TP; phi pooled in-epilogue -> Pt[m][c]
    gemm_bt_kernel<3><<<dim3(4,32,Bn), 256, 0, stream>>>(xT, (long)HW*Cc, wall, 0, TP, (long)HW*512,
                                                         HW, 512, Cc, ball, Pt);
    // Gg GEMM: C never materialized; pooled in-epilogue -> G[c][m]
    gemm_bt_kernel<4><<<dim3(32,2,Bn), 256, 0, stream>>>(wall + (size_t)512*512, 0, xT, (long)HW*Cc,
                                                         G, (long)CI*Mp, CI, HW, Cc, ball + 512, nullptr);
    // fused scores+softmax+PV+outconv+BN+residual -> out
    fused_attn_kernel<<<1024, 256, 0, stream>>>(TP, Pt, G, wo, scale, shift, x, out);
}

// Round 21
// 221.088 us; speedup vs baseline: 1.3971x; 1.2520x over previous
//
#include <hip/hip_runtime.h>

typedef _Float16 v8h __attribute__((ext_vector_type(8)));
typedef _Float16 v4h __attribute__((ext_vector_type(4)));
typedef float v4f __attribute__((ext_vector_type(4)));
#define HF _Float16

// dims
#define Bn 8
#define Cc 512
#define CI 256
#define HW 4096   // 64*64
#define Mp 1024   // 32*32 pooled

__device__ __forceinline__ void gload16(const void* g, void* l) {
    __builtin_amdgcn_global_load_lds((const __attribute__((address_space(1))) void*)g,
                                     (__attribute__((address_space(3))) void*)l, 16, 0, 0);
}

// ---------------- prep: weights fp32->f16, BN fold ----------------
__global__ __launch_bounds__(256) void prep_kernel(
    const float* __restrict__ w_g, const float* __restrict__ b_g,
    const float* __restrict__ w_th, const float* __restrict__ b_th,
    const float* __restrict__ w_ph, const float* __restrict__ b_ph,
    const float* __restrict__ w_out, const float* __restrict__ b_out,
    const float* __restrict__ gamma, const float* __restrict__ beta,
    const float* __restrict__ mean, const float* __restrict__ var,
    HF* __restrict__ wall, float* __restrict__ ball,
    HF* __restrict__ wo, float* __restrict__ scale, float* __restrict__ shift)
{
    int idx = blockIdx.x * 256 + threadIdx.x;
    if (idx < 768*512) {
        int o = idx >> 9;
        float v = (o < 256) ? w_th[idx] : (o < 512) ? w_ph[idx - 256*512] : w_g[idx - 512*512];
        wall[idx] = (HF)v;
    }
    if (idx < 512*256) wo[idx] = (HF)w_out[idx];
    if (idx < 768) ball[idx] = (idx < 256) ? b_th[idx] : (idx < 512) ? b_ph[idx-256] : b_g[idx-512];
    if (idx < 512) {
        float inv = gamma[idx] * rsqrtf(var[idx] + 1e-5f);
        scale[idx] = inv;
        shift[idx] = (b_out[idx] - mean[idx]) * inv + beta[idx];
    }
}

// ---------------- transpose x: (b,c,s) fp32 -> xT (b,s,c) f16 ----------------
__global__ __launch_bounds__(256) void transpose_x_kernel(const float* __restrict__ x, HF* __restrict__ xT)
{
    __shared__ float tile[64][65];
    int b = blockIdx.z;
    int c0 = blockIdx.y * 64, s0 = blockIdx.x * 64;
    int tr = threadIdx.x >> 6, ts = threadIdx.x & 63;
    #pragma unroll
    for (int i = 0; i < 16; ++i) {
        int r = tr + i*4;
        tile[r][ts] = x[((long)(b*Cc) + c0 + r)*HW + s0 + ts];
    }
    __syncthreads();
    #pragma unroll
    for (int i = 0; i < 16; ++i) {
        int r = tr + i*4;
        xT[((long)b*HW + s0 + r)*Cc + c0 + ts] = (HF)tile[ts][r];
    }
}

// ---------------- gemm_bt with fused pool epilogues ----------------
// C[i,j] = sum_k A[i,k]*B[j,k]. reg-staged, padded LDS, 2 barriers/step.
// EPI 3 (TP):  theta cols (j0<256) -> C f16 = acc + colBias[j] to Cv.
//              phi cols (j0>=256) -> pool rows (s) 2x2 -> aux = Pt[m][c].
// EPI 4 (Gg):  pool cols (s) 2x2 -> Cv = G[c][m] ONLY (Gg never materialized).
template<int EPI>
__global__ __launch_bounds__(256) void gemm_bt_kernel(
    const HF* __restrict__ A, long sA, const HF* __restrict__ B, long sB,
    void* __restrict__ Cv, long sC, int M, int N, int K,
    const float* __restrict__ bias, HF* __restrict__ aux)
{
    __shared__ union USm {
        struct { alignas(16) HF As[128][40]; alignas(16) HF Bs[128][40]; } s;
        alignas(16) HF Ct[128][132];   // epilogue pool buffer (As/Bs dead)
    } u;
    int b = blockIdx.z;
    int i0 = blockIdx.y * 128;
    int j0 = blockIdx.x * 128;
    const HF* Ab = A + (long)b * sA;
    const HF* Bb = B + (long)b * sB;
    int tid = threadIdx.x;
    int lane = tid & 63, w = tid >> 6;
    int wr = w >> 1, wc = w & 1;
    int lr = lane & 15, lk = (lane >> 4) * 8;

    v4f acc[4][4];
    #pragma unroll
    for (int i = 0; i < 4; ++i)
        #pragma unroll
        for (int j = 0; j < 4; ++j) { v4f z = {0.f,0.f,0.f,0.f}; acc[i][j] = z; }

    for (int k0 = 0; k0 < K; k0 += 32) {
        #pragma unroll
        for (int q = 0; q < 2; ++q) {
            int ch = tid*2 + q;          // 0..511
            int row = ch >> 2;
            int c8 = (ch & 3) * 8;
            const uint4* ga = (const uint4*)(Ab + (long)(i0+row)*K + k0 + c8);
            *(uint4*)(&u.s.As[row][c8]) = *ga;
            const uint4* gb = (const uint4*)(Bb + (long)(j0+row)*K + k0 + c8);
            *(uint4*)(&u.s.Bs[row][c8]) = *gb;
        }
        __syncthreads();
        v8h af[4], bfr[4];
        #pragma unroll
        for (int mf = 0; mf < 4; ++mf)
            af[mf] = *(const v8h*)(&u.s.As[wr*64 + mf*16 + lr][lk]);
        #pragma unroll
        for (int nf = 0; nf < 4; ++nf)
            bfr[nf] = *(const v8h*)(&u.s.Bs[wc*64 + nf*16 + lr][lk]);
        #pragma unroll
        for (int mf = 0; mf < 4; ++mf)
            #pragma unroll
            for (int nf = 0; nf < 4; ++nf)
                acc[mf][nf] = __builtin_amdgcn_mfma_f32_16x16x32_f16(af[mf], bfr[nf], acc[mf][nf], 0, 0, 0);
        __syncthreads();
    }

    int rbase = (lane >> 4) * 4;
    bool pooled = (EPI == 4) || (EPI == 3 && j0 >= 256);
    #pragma unroll
    for (int mf = 0; mf < 4; ++mf) {
        #pragma unroll
        for (int nf = 0; nf < 4; ++nf) {
            #pragma unroll
            for (int r = 0; r < 4; ++r) {
                int rloc = wr*64 + mf*16 + rbase + r;
                int cloc = wc*64 + nf*16 + lr;
                float v = acc[mf][nf][r];
                if (EPI == 3) v += bias[j0 + cloc];        // colBias (o)
                else          v += bias[i0 + rloc];        // rowBias (c)
                if (pooled) {
                    u.Ct[rloc][cloc] = (HF)v;
                } else {  // EPI==3 theta: direct write
                    ((HF*)Cv + (long)b*sC)[(long)(i0 + rloc)*N + j0 + cloc] = (HF)v;
                }
            }
        }
    }

    if (pooled) {
        __syncthreads();
        if (EPI == 3) {
            // pool over ROWS (s): rows {2m,2m+1,64+2m,64+2m+1} -> Pt[m0+m][j0-256 + oc]
            int m = tid >> 3, oc = (tid & 7) * 16;
            int m0 = (i0 >> 7) * 32;
            HF* Pt_ = aux + (long)b*Mp*CI;
            HF res[16];
            #pragma unroll
            for (int j = 0; j < 16; ++j) {
                float v0 = fmaxf((float)u.Ct[2*m][oc+j],    (float)u.Ct[2*m+1][oc+j]);
                float v1 = fmaxf((float)u.Ct[64+2*m][oc+j], (float)u.Ct[64+2*m+1][oc+j]);
                res[j] = (HF)fmaxf(v0, v1);
            }
            HF* dst = Pt_ + (long)(m0 + m)*CI + (j0 - 256) + oc;
            *(v8h*)dst = *(v8h*)&res[0];
            *(v8h*)(dst + 8) = *(v8h*)&res[8];
        } else {
            // pool over COLS (s): G[i0+c][m0 + mg..mg+15]
            int c = tid >> 1, mg = (tid & 1) * 16;
            int m0 = (j0 >> 7) * 32;
            HF* Gp = (HF*)Cv + (long)b*sC;
            HF res[16];
            #pragma unroll
            for (int j = 0; j < 16; ++j) {
                int mm = mg + j;
                float v0 = fmaxf((float)u.Ct[c][2*mm],    (float)u.Ct[c][2*mm+1]);
                float v1 = fmaxf((float)u.Ct[c][64+2*mm], (float)u.Ct[c][64+2*mm+1]);
                res[j] = (HF)fmaxf(v0, v1);
            }
            HF* dst = Gp + (long)(i0 + c)*Mp + m0 + mg;
            *(v8h*)dst = *(v8h*)&res[0];
            *(v8h*)(dst + 8) = *(v8h*)&res[8];
        }
    }
}

// ---------------- fused flash attention v17: 64-row tiles, 512 blocks x 512 thr ----
// 8 waves/block (waves 0-3 = producers: swapped QK^T + softmax, 16 rows each,
// IDENTICAL indexing to r18; all 8 waves = consumers: c-split PV 32 cols each +
// fused out-conv epilogue co-slab 64 rows each). Same 512 blocks => per-block
// fixed costs (P stage, G loads, wo reads) unchanged vs r18; waves/CU doubles
// (2 blocks x 8 waves = 16) if VGPR <= 128. LDS ~43 KB (union Y over P bufs).
__global__ __launch_bounds__(512, 2) void fused_attn_kernel(
    const HF* __restrict__ TP,   // [B][4096][512], theta = cols 0..255
    const HF* __restrict__ Pt,   // [B][1024][256]
    const HF* __restrict__ G,    // [B][256][1024]
    const HF* __restrict__ wo,   // [512][256]
    const float* __restrict__ scale, const float* __restrict__ shift,
    const float* __restrict__ x, // [B][512][4096] fp32
    float* __restrict__ out)     // [B][512][4096] fp32
{
    __shared__ union SMem {
        struct {
            alignas(16) HF P_lds[2][8192];      // [32 kg][32 row][8] k-group-major
            alignas(16) HF P_buf[2][4][16][36]; // [pb][rowgrp][n 16][m 32+4pad]
            alignas(16) float smem_a[2][4][16]; // [pb][rowgrp][n] alpha
        } m;
        alignas(16) HF Y[64][264];              // epilogue: normalized Y (row 528B)
    } sm;
    __shared__ float smem_l[64];                // final row sums

    int bid = blockIdx.x;
    int b = bid & 7;
    int ntile = bid >> 3;          // 0..63
    int tid = threadIdx.x;
    int lane = tid & 63, w = tid >> 6;   // w in 0..7
    int lr = lane & 15, lkg = lane >> 4;
    int nbase = ntile * 64;

    const HF* Pb = Pt + (long)b*Mp*CI;
    const HF* Gb = G  + (long)b*CI*Mp + (long)(w*32)*Mp;     // my 32-col slice

    auto stage = [&](int bsel, int m0) {
        #pragma unroll
        for (int q = 0; q < 2; ++q) {
            int idxp = (w*2 + q)*64 + lane;         // 0..1023; dest = idxp*16B
            int pkg = idxp >> 5, prow = idxp & 31;  // [32 kg][32 row][8]
            gload16(Pb + (long)(m0 + prow)*CI + pkg*8, sm.m.P_lds[bsel] + (size_t)idxp*8);
        }
    };
    auto loadG = [&](int m0, v8h* g) {
        #pragma unroll
        for (int ct = 0; ct < 2; ++ct)
            g[ct] = *(const v8h*)(Gb + (long)(ct*16 + lr)*Mp + m0 + lkg*8);
    };

    // Q fragments (producers w<4 only; rows nbase + w*16 + lr)
    v8h af[8];
    if (w < 4) {
        const HF* Tq = TP + ((long)b*HW + nbase + w*16) * 512;
        #pragma unroll
        for (int kf = 0; kf < 8; ++kf)
            af[kf] = *(const v8h*)(Tq + (long)lr*512 + kf*32 + lkg*8);
    }

    v4f acc_y[4][2];   // [row-tile rt][c-tile ct]; Y row = rt*16+lkg*4+r, col = w*32+ct*16+lr
    #pragma unroll
    for (int i = 0; i < 4; ++i)
        #pragma unroll
        for (int j = 0; j < 2; ++j) { v4f z = {0.f,0.f,0.f,0.f}; acc_y[i][j] = z; }
    float mrun = -1e30f;   // (producers) running max for my row n = nbase + w*16 + lr
    float lsum = 0.f;      // (producers) per-lane partial sum over my m's

    v8h gA[2], gB[2];
    stage(0, 0);
    loadG(0, gA);
    __syncthreads();

    for (int t = 0; t < 32; ++t) {
        int cur = t & 1;
        int pb = t & 1;
        v8h* gcur  = (t & 1) ? gB : gA;
        v8h* gnext = (t & 1) ? gA : gB;
        if (t < 31) {
            stage(cur ^ 1, (t+1)*32);     // gload_lds next P chunk
            loadG((t+1)*32, gnext);       // G regs next chunk (issue-early)
        }

        if (w < 4) {
            // QK^T swapped: acc[mt] holds S[n=lr][m = mt*16 + lkg*4 + r]
            v4f acc[2];
            #pragma unroll
            for (int mt = 0; mt < 2; ++mt) { v4f z = {0.f,0.f,0.f,0.f}; acc[mt] = z; }
            __builtin_amdgcn_s_setprio(1);
            #pragma unroll
            for (int kf = 0; kf < 8; ++kf) {
                #pragma unroll
                for (int mt = 0; mt < 2; ++mt) {
                    v8h pf = *(const v8h*)(sm.m.P_lds[cur] + (kf*4 + lkg)*256 + (mt*16 + lr)*8);
                    acc[mt] = __builtin_amdgcn_mfma_f32_16x16x32_f16(pf, af[kf], acc[mt], 0, 0, 0);
                }
            }
            __builtin_amdgcn_s_setprio(0);

            // softmax: per-lane row n=lr. 7 in-lane max + 2 shuffles.
            float cm = fmaxf(fmaxf(fmaxf(acc[0][0], acc[0][1]), fmaxf(acc[0][2], acc[0][3])),
                             fmaxf(fmaxf(acc[1][0], acc[1][1]), fmaxf(acc[1][2], acc[1][3])));
            cm = fmaxf(cm, __shfl_xor(cm, 16));
            cm = fmaxf(cm, __shfl_xor(cm, 32));
            float alpha = 1.f;
            if (cm > mrun + 7.f) {            // defer: p <= e^7 = 1096, f16-safe
                alpha = __expf(mrun - cm);    // first iter: exp(-inf)=0 zeroes empty acc
                mrun = cm;
                lsum *= alpha;
            }
            if (lane < 16) sm.m.smem_a[pb][w][lr] = alpha;
            #pragma unroll
            for (int mt = 0; mt < 2; ++mt) {
                v4h p4;
                #pragma unroll
                for (int r = 0; r < 4; ++r) {
                    float p = __expf(acc[mt][r] - mrun);
                    lsum += p;
                    p4[r] = (HF)p;
                }
                *(v4h*)(&sm.m.P_buf[pb][w][lr][mt*16 + lkg*4]) = p4;   // one b64 per mt
            }
        }

        __syncthreads();   // P_buf[pb]+smem_a[pb] visible; vmcnt drained

        // PV (all 8 waves): Y[64 n][my 32 c] += P(64x32) @ G^T (G in registers)
        __builtin_amdgcn_s_setprio(1);
        v4f alv[4];
        bool need = false;
        #pragma unroll
        for (int rt = 0; rt < 4; ++rt) {
            alv[rt] = *(const v4f*)(&sm.m.smem_a[pb][rt][lkg*4]);
            need = need | (alv[rt][0] != 1.f) | (alv[rt][1] != 1.f)
                        | (alv[rt][2] != 1.f) | (alv[rt][3] != 1.f);
        }
        if (__any(need)) {
            #pragma unroll
            for (int rt = 0; rt < 4; ++rt)
                #pragma unroll
                for (int ct = 0; ct < 2; ++ct)
                    #pragma unroll
                    for (int r = 0; r < 4; ++r)
                        acc_y[rt][ct][r] *= alv[rt][r];
        }
        #pragma unroll
        for (int rt = 0; rt < 4; ++rt) {
            v8h ap;
            {
                v4h a0 = *(const v4h*)(&sm.m.P_buf[pb][rt][lr][lkg*8]);
                v4h a1 = *(const v4h*)(&sm.m.P_buf[pb][rt][lr][lkg*8 + 4]);
                ap = __builtin_shufflevector(a0, a1, 0,1,2,3,4,5,6,7);
            }
            #pragma unroll
            for (int ct = 0; ct < 2; ++ct)
                acc_y[rt][ct] = __builtin_amdgcn_mfma_f32_16x16x32_f16(ap, gcur[ct], acc_y[rt][ct], 0, 0, 0);
        }
        __builtin_amdgcn_s_setprio(0);
    }

    // ---- epilogue 1: row sums (producers), normalize Y into LDS (union overlay) ----
    if (w < 4) {
        lsum += __shfl_xor(lsum, 16);
        lsum += __shfl_xor(lsum, 32);
        if (lane < 16) smem_l[w*16 + lr] = lsum;
    }
    __syncthreads();
    #pragma unroll
    for (int rt = 0; rt < 4; ++rt) {
        #pragma unroll
        for (int r = 0; r < 4; ++r) {
            int row = rt*16 + lkg*4 + r;
            float inv = 1.f / smem_l[row];
            #pragma unroll
            for (int ct = 0; ct < 2; ++ct)
                sm.Y[row][w*32 + ct*16 + lr] = (HF)(acc_y[rt][ct][r] * inv);
        }
    }
    __syncthreads();

    // ---- epilogue 2: out[co][n] = (wo @ Y^T) * scale + shift + x, 64-co slab per wave ----
    const HF* wob = wo + (long)(w*64)*CI;   // my 64 co rows
    v4f acc2[4][4];
    #pragma unroll
    for (int i = 0; i < 4; ++i)
        #pragma unroll
        for (int j = 0; j < 4; ++j) { v4f z = {0.f,0.f,0.f,0.f}; acc2[i][j] = z; }
    #pragma unroll
    for (int kf = 0; kf < 8; ++kf) {
        v8h bf2[4];
        #pragma unroll
        for (int nt = 0; nt < 4; ++nt)
            bf2[nt] = *(const v8h*)(&sm.Y[nt*16 + lr][kf*32 + lkg*8]);
        #pragma unroll
        for (int cot = 0; cot < 4; ++cot) {
            v8h af2 = *(const v8h*)(wob + (long)(cot*16 + lr)*CI + kf*32 + lkg*8);
            #pragma unroll
            for (int nt = 0; nt < 4; ++nt)
                acc2[cot][nt] = __builtin_amdgcn_mfma_f32_16x16x32_f16(af2, bf2[nt], acc2[cot][nt], 0, 0, 0);
        }
    }
    const float* xb = x + (long)b*Cc*HW + nbase;
    float* ob = out + (long)b*Cc*HW + nbase;
    #pragma unroll
    for (int cot = 0; cot < 4; ++cot) {
        int co = w*64 + cot*16 + lkg*4;
        #pragma unroll
        for (int r = 0; r < 4; ++r) {
            float sc = scale[co + r], sh = shift[co + r];
            #pragma unroll
            for (int nt = 0; nt < 4; ++nt) {
                long o = (long)(co + r)*HW + nt*16 + lr;
                ob[o] = acc2[cot][nt][r] * sc + sh + xb[o];
            }
        }
    }
}

extern "C" void kernel_launch(void* const* d_in, const int* in_sizes, int n_in,
                              void* d_out, int out_size, void* d_ws, size_t ws_size,
                              hipStream_t stream)
{
    const float* x     = (const float*)d_in[0];
    const float* w_g   = (const float*)d_in[1];
    const float* b_g   = (const float*)d_in[2];
    const float* w_th  = (const float*)d_in[3];
    const float* b_th  = (const float*)d_in[4];
    const float* w_ph  = (const float*)d_in[5];
    const float* b_ph  = (const float*)d_in[6];
    const float* w_out = (const float*)d_in[7];
    const float* b_out = (const float*)d_in[8];
    const float* gamma = (const float*)d_in[9];
    const float* beta  = (const float*)d_in[10];
    const float* mean  = (const float*)d_in[11];
    const float* var   = (const float*)d_in[12];
    float* out = (float*)d_out;

    char* ws = (char*)d_ws;
    size_t off = 0;
    auto alloc = [&](size_t bytes) { void* p = ws + off; off += (bytes + 255) & ~(size_t)255; return p; };
    HF*    wall  = (HF*)alloc((size_t)768*512*2);   // rows: theta 0-255, phi 256-511, g 512-767
    float* ball  = (float*)alloc(768*4);
    HF*    wo    = (HF*)alloc((size_t)512*256*2);
    float* scale = (float*)alloc(512*4);
    float* shift = (float*)alloc(512*4);
    HF*    xT    = (HF*)alloc((size_t)Bn*HW*Cc*2);
    HF*    TP    = (HF*)alloc((size_t)Bn*HW*512*2);  // [s][theta|phi] (phi half unused)
    HF*    Pt    = (HF*)alloc((size_t)Bn*Mp*CI*2);
    HF*    G     = (HF*)alloc((size_t)Bn*CI*Mp*2);

    prep_kernel<<<1536, 256, 0, stream>>>(w_g,b_g,w_th,b_th,w_ph,b_ph,w_out,b_out,gamma,beta,mean,var,
                                          wall, ball, wo, scale, shift);
    transpose_x_kernel<<<dim3(64,8,Bn), 256, 0, stream>>>(x, xT);
    // TP GEMM: theta written to TP; phi pooled in-epilogue -> Pt[m][c]
    gemm_bt_kernel<3><<<dim3(4,32,Bn), 256, 0, stream>>>(xT, (long)HW*Cc, wall, 0, TP, (long)HW*512,
                                                         HW, 512, Cc, ball, Pt);
    // Gg GEMM: C never materialized; pooled in-epilogue -> G[c][m]
    gemm_bt_kernel<4><<<dim3(32,2,Bn), 256, 0, stream>>>(wall + (size_t)512*512, 0, xT, (long)HW*Cc,
                                                         G, (long)CI*Mp, CI, HW, Cc, ball + 512, nullptr);
    // fused scores+softmax+PV+outconv+BN+residual -> out
    fused_attn_kernel<<<512, 512, 0, stream>>>(TP, Pt, G, wo, scale, shift, x, out);
}

// Round 22
// 184.939 us; speedup vs baseline: 1.6702x; 1.1955x over previous
//
#include <hip/hip_runtime.h>

typedef _Float16 v8h __attribute__((ext_vector_type(8)));
typedef _Float16 v4h __attribute__((ext_vector_type(4)));
typedef float v4f __attribute__((ext_vector_type(4)));
#define HF _Float16

// dims
#define Bn 8
#define Cc 512
#define CI 256
#define HW 4096   // 64*64
#define Mp 1024   // 32*32 pooled

__device__ __forceinline__ void gload16(const void* g, void* l) {
    __builtin_amdgcn_global_load_lds((const __attribute__((address_space(1))) void*)g,
                                     (__attribute__((address_space(3))) void*)l, 16, 0, 0);
}

// ---------------- prep: weights fp32->f16, BN fold ----------------
__global__ __launch_bounds__(256) void prep_kernel(
    const float* __restrict__ w_g, const float* __restrict__ b_g,
    const float* __restrict__ w_th, const float* __restrict__ b_th,
    const float* __restrict__ w_ph, const float* __restrict__ b_ph,
    const float* __restrict__ w_out, const float* __restrict__ b_out,
    const float* __restrict__ gamma, const float* __restrict__ beta,
    const float* __restrict__ mean, const float* __restrict__ var,
    HF* __restrict__ wall, float* __restrict__ ball,
    HF* __restrict__ wo, float* __restrict__ scale, float* __restrict__ shift)
{
    int idx = blockIdx.x * 256 + threadIdx.x;
    if (idx < 768*512) {
        int o = idx >> 9;
        float v = (o < 256) ? w_th[idx] : (o < 512) ? w_ph[idx - 256*512] : w_g[idx - 512*512];
        wall[idx] = (HF)v;
    }
    if (idx < 512*256) wo[idx] = (HF)w_out[idx];
    if (idx < 768) ball[idx] = (idx < 256) ? b_th[idx] : (idx < 512) ? b_ph[idx-256] : b_g[idx-512];
    if (idx < 512) {
        float inv = gamma[idx] * rsqrtf(var[idx] + 1e-5f);
        scale[idx] = inv;
        shift[idx] = (b_out[idx] - mean[idx]) * inv + beta[idx];
    }
}

// ---------------- transpose x: (b,c,s) fp32 -> xT (b,s,c) f16 ----------------
__global__ __launch_bounds__(256) void transpose_x_kernel(const float* __restrict__ x, HF* __restrict__ xT)
{
    __shared__ float tile[64][65];
    int b = blockIdx.z;
    int c0 = blockIdx.y * 64, s0 = blockIdx.x * 64;
    int tr = threadIdx.x >> 6, ts = threadIdx.x & 63;
    #pragma unroll
    for (int i = 0; i < 16; ++i) {
        int r = tr + i*4;
        tile[r][ts] = x[((long)(b*Cc) + c0 + r)*HW + s0 + ts];
    }
    __syncthreads();
    #pragma unroll
    for (int i = 0; i < 16; ++i) {
        int r = tr + i*4;
        xT[((long)b*HW + s0 + r)*Cc + c0 + ts] = (HF)tile[ts][r];
    }
}

// ---------------- gemm_bt with fused pool epilogues ----------------
// C[i,j] = sum_k A[i,k]*B[j,k]. reg-staged, padded LDS, 2 barriers/step.
// EPI 3 (TP):  theta cols (j0<256) -> C f16 = acc + colBias[j] to Cv.
//              phi cols (j0>=256) -> pool rows (s) 2x2 -> aux = Pt[m][c].
// EPI 4 (Gg):  pool cols (s) 2x2 -> Cv = G[c][m] ONLY (Gg never materialized).
template<int EPI>
__global__ __launch_bounds__(256) void gemm_bt_kernel(
    const HF* __restrict__ A, long sA, const HF* __restrict__ B, long sB,
    void* __restrict__ Cv, long sC, int M, int N, int K,
    const float* __restrict__ bias, HF* __restrict__ aux)
{
    __shared__ union USm {
        struct { alignas(16) HF As[128][40]; alignas(16) HF Bs[128][40]; } s;
        alignas(16) HF Ct[128][132];   // epilogue pool buffer (As/Bs dead)
    } u;
    int b = blockIdx.z;
    int i0 = blockIdx.y * 128;
    int j0 = blockIdx.x * 128;
    const HF* Ab = A + (long)b * sA;
    const HF* Bb = B + (long)b * sB;
    int tid = threadIdx.x;
    int lane = tid & 63, w = tid >> 6;
    int wr = w >> 1, wc = w & 1;
    int lr = lane & 15, lk = (lane >> 4) * 8;

    v4f acc[4][4];
    #pragma unroll
    for (int i = 0; i < 4; ++i)
        #pragma unroll
        for (int j = 0; j < 4; ++j) { v4f z = {0.f,0.f,0.f,0.f}; acc[i][j] = z; }

    for (int k0 = 0; k0 < K; k0 += 32) {
        #pragma unroll
        for (int q = 0; q < 2; ++q) {
            int ch = tid*2 + q;          // 0..511
            int row = ch >> 2;
            int c8 = (ch & 3) * 8;
            const uint4* ga = (const uint4*)(Ab + (long)(i0+row)*K + k0 + c8);
            *(uint4*)(&u.s.As[row][c8]) = *ga;
            const uint4* gb = (const uint4*)(Bb + (long)(j0+row)*K + k0 + c8);
            *(uint4*)(&u.s.Bs[row][c8]) = *gb;
        }
        __syncthreads();
        v8h af[4], bfr[4];
        #pragma unroll
        for (int mf = 0; mf < 4; ++mf)
            af[mf] = *(const v8h*)(&u.s.As[wr*64 + mf*16 + lr][lk]);
        #pragma unroll
        for (int nf = 0; nf < 4; ++nf)
            bfr[nf] = *(const v8h*)(&u.s.Bs[wc*64 + nf*16 + lr][lk]);
        #pragma unroll
        for (int mf = 0; mf < 4; ++mf)
            #pragma unroll
            for (int nf = 0; nf < 4; ++nf)
                acc[mf][nf] = __builtin_amdgcn_mfma_f32_16x16x32_f16(af[mf], bfr[nf], acc[mf][nf], 0, 0, 0);
        __syncthreads();
    }

    int rbase = (lane >> 4) * 4;
    bool pooled = (EPI == 4) || (EPI == 3 && j0 >= 256);
    #pragma unroll
    for (int mf = 0; mf < 4; ++mf) {
        #pragma unroll
        for (int nf = 0; nf < 4; ++nf) {
            #pragma unroll
            for (int r = 0; r < 4; ++r) {
                int rloc = wr*64 + mf*16 + rbase + r;
                int cloc = wc*64 + nf*16 + lr;
                float v = acc[mf][nf][r];
                if (EPI == 3) v += bias[j0 + cloc];        // colBias (o)
                else          v += bias[i0 + rloc];        // rowBias (c)
                if (pooled) {
                    u.Ct[rloc][cloc] = (HF)v;
                } else {  // EPI==3 theta: direct write
                    ((HF*)Cv + (long)b*sC)[(long)(i0 + rloc)*N + j0 + cloc] = (HF)v;
                }
            }
        }
    }

    if (pooled) {
        __syncthreads();
        if (EPI == 3) {
            // pool over ROWS (s): rows {2m,2m+1,64+2m,64+2m+1} -> Pt[m0+m][j0-256 + oc]
            int m = tid >> 3, oc = (tid & 7) * 16;
            int m0 = (i0 >> 7) * 32;
            HF* Pt_ = aux + (long)b*Mp*CI;
            HF res[16];
            #pragma unroll
            for (int j = 0; j < 16; ++j) {
                float v0 = fmaxf((float)u.Ct[2*m][oc+j],    (float)u.Ct[2*m+1][oc+j]);
                float v1 = fmaxf((float)u.Ct[64+2*m][oc+j], (float)u.Ct[64+2*m+1][oc+j]);
                res[j] = (HF)fmaxf(v0, v1);
            }
            HF* dst = Pt_ + (long)(m0 + m)*CI + (j0 - 256) + oc;
            *(v8h*)dst = *(v8h*)&res[0];
            *(v8h*)(dst + 8) = *(v8h*)&res[8];
        } else {
            // pool over COLS (s): G[i0+c][m0 + mg..mg+15]
            int c = tid >> 1, mg = (tid & 1) * 16;
            int m0 = (j0 >> 7) * 32;
            HF* Gp = (HF*)Cv + (long)b*sC;
            HF res[16];
            #pragma unroll
            for (int j = 0; j < 16; ++j) {
                int mm = mg + j;
                float v0 = fmaxf((float)u.Ct[c][2*mm],    (float)u.Ct[c][2*mm+1]);
                float v1 = fmaxf((float)u.Ct[c][64+2*mm], (float)u.Ct[c][64+2*mm+1]);
                res[j] = (HF)fmaxf(v0, v1);
            }
            HF* dst = Gp + (long)(i0 + c)*Mp + m0 + mg;
            *(v8h*)dst = *(v8h*)&res[0];
            *(v8h*)(dst + 8) = *(v8h*)&res[8];
        }
    }
}

// ---------------- fused flash attention (r18 configuration — measured optimum) ----------
// 512 blocks x 256 thr (4 waves), 2 blocks/CU. batch = bid&7 (XCD-pinned).
// Swapped QK^T, c-split PV, defer-rescale THR=7, G regs from L2 (1 iter ahead),
// P staged via gload_lds double-buffer; fused out-conv+BN+residual epilogue.
// Y_lds unioned over {P_lds, P_buf, smem_a} (epilogue-only).
__global__ __launch_bounds__(256, 2) void fused_attn_kernel(
    const HF* __restrict__ TP,   // [B][4096][512], theta = cols 0..255
    const HF* __restrict__ Pt,   // [B][1024][256]
    const HF* __restrict__ G,    // [B][256][1024]
    const HF* __restrict__ wo,   // [512][256]
    const float* __restrict__ scale, const float* __restrict__ shift,
    const float* __restrict__ x, // [B][512][4096] fp32
    float* __restrict__ out)     // [B][512][4096] fp32
{
    __shared__ union SMem {
        struct {
            alignas(16) HF P_lds[2][8192];      // [32 kg][32 row][8] k-group-major
            alignas(16) HF P_buf[2][4][16][36]; // [pb][rowgrp][n 16][m 32+4pad]
            alignas(16) float smem_a[2][4][16]; // [pb][rowgrp][n] alpha
        } m;
        alignas(16) HF Y[64][264];              // epilogue: normalized Y (row 528B)
    } sm;
    __shared__ float smem_l[64];                // final row sums

    int bid = blockIdx.x;
    int b = bid & 7;
    int ntile = bid >> 3;          // 0..63
    int tid = threadIdx.x;
    int lane = tid & 63, w = tid >> 6;
    int lr = lane & 15, lkg = lane >> 4;
    int nbase = ntile * 64;

    const HF* Tq = TP + ((long)b*HW + nbase + w*16) * 512;   // my 16 softmax rows
    const HF* Pb = Pt + (long)b*Mp*CI;
    const HF* Gb = G  + (long)b*CI*Mp + (long)(w*64)*Mp;     // my c-quadrant

    auto stage = [&](int bsel, int m0) {
        #pragma unroll
        for (int q = 0; q < 4; ++q) {
            int idxp = (w*4 + q)*64 + lane;         // 0..1023; dest = idxp*16B
            int pkg = idxp >> 5, prow = idxp & 31;  // [32 kg][32 row][8]
            gload16(Pb + (long)(m0 + prow)*CI + pkg*8, sm.m.P_lds[bsel] + (size_t)idxp*8);
        }
    };
    auto loadG = [&](int m0, v8h* g) {
        #pragma unroll
        for (int ct = 0; ct < 4; ++ct)
            g[ct] = *(const v8h*)(Gb + (long)(ct*16 + lr)*Mp + m0 + lkg*8);
    };

    // Q fragments in registers for whole kernel (theta cols of TP)
    v8h af[8];
    #pragma unroll
    for (int kf = 0; kf < 8; ++kf)
        af[kf] = *(const v8h*)(Tq + (long)lr*512 + kf*32 + lkg*8);

    v4f acc_y[4][4];   // [row-tile rt][c-tile ct]; Y row = rt*16+lkg*4+r, col = w*64+ct*16+lr
    #pragma unroll
    for (int i = 0; i < 4; ++i)
        #pragma unroll
        for (int j = 0; j < 4; ++j) { v4f z = {0.f,0.f,0.f,0.f}; acc_y[i][j] = z; }
    float mrun = -1e30f;   // running max for my row n = nbase + w*16 + lr
    float lsum = 0.f;      // per-lane partial sum over my m's

    v8h gA[4], gB[4];
    stage(0, 0);
    loadG(0, gA);
    __syncthreads();

    for (int t = 0; t < 32; ++t) {
        int cur = t & 1;
        int pb = t & 1;
        v8h* gcur  = (t & 1) ? gB : gA;
        v8h* gnext = (t & 1) ? gA : gB;
        if (t < 31) {
            stage(cur ^ 1, (t+1)*32);     // gload_lds next P chunk
            loadG((t+1)*32, gnext);       // G regs next chunk (issue-early)
        }

        // QK^T swapped: acc[mt] holds S[n=lr][m = mt*16 + lkg*4 + r]
        v4f acc[2];
        #pragma unroll
        for (int mt = 0; mt < 2; ++mt) { v4f z = {0.f,0.f,0.f,0.f}; acc[mt] = z; }
        __builtin_amdgcn_s_setprio(1);
        #pragma unroll
        for (int kf = 0; kf < 8; ++kf) {
            #pragma unroll
            for (int mt = 0; mt < 2; ++mt) {
                v8h pf = *(const v8h*)(sm.m.P_lds[cur] + (kf*4 + lkg)*256 + (mt*16 + lr)*8);
                acc[mt] = __builtin_amdgcn_mfma_f32_16x16x32_f16(pf, af[kf], acc[mt], 0, 0, 0);
            }
        }
        __builtin_amdgcn_s_setprio(0);

        // softmax: per-lane row n=lr. 7 in-lane max + 2 shuffles.
        float cm = fmaxf(fmaxf(fmaxf(acc[0][0], acc[0][1]), fmaxf(acc[0][2], acc[0][3])),
                         fmaxf(fmaxf(acc[1][0], acc[1][1]), fmaxf(acc[1][2], acc[1][3])));
        cm = fmaxf(cm, __shfl_xor(cm, 16));
        cm = fmaxf(cm, __shfl_xor(cm, 32));
        float alpha = 1.f;
        if (cm > mrun + 7.f) {            // defer: p <= e^7 = 1096, f16-safe
            alpha = __expf(mrun - cm);    // first iter: exp(-inf)=0 zeroes empty acc
            mrun = cm;
            lsum *= alpha;
        }
        if (lane < 16) sm.m.smem_a[pb][w][lr] = alpha;
        #pragma unroll
        for (int mt = 0; mt < 2; ++mt) {
            v4h p4;
            #pragma unroll
            for (int r = 0; r < 4; ++r) {
                float p = __expf(acc[mt][r] - mrun);
                lsum += p;
                p4[r] = (HF)p;
            }
            *(v4h*)(&sm.m.P_buf[pb][w][lr][mt*16 + lkg*4]) = p4;   // one b64 per mt
        }

        __syncthreads();   // P_buf[pb]+smem_a[pb] visible; vmcnt drained

        // PV: Y[64 n][my 64 c] += P(64x32) @ G^T (G in registers)
        __builtin_amdgcn_s_setprio(1);
        v4f alv[4];
        bool need = false;
        #pragma unroll
        for (int rt = 0; rt < 4; ++rt) {
            alv[rt] = *(const v4f*)(&sm.m.smem_a[pb][rt][lkg*4]);
            need = need | (alv[rt][0] != 1.f) | (alv[rt][1] != 1.f)
                        | (alv[rt][2] != 1.f) | (alv[rt][3] != 1.f);
        }
        if (__any(need)) {
            #pragma unroll
            for (int rt = 0; rt < 4; ++rt)
                #pragma unroll
                for (int ct = 0; ct < 4; ++ct)
                    #pragma unroll
                    for (int r = 0; r < 4; ++r)
                        acc_y[rt][ct][r] *= alv[rt][r];
        }
        #pragma unroll
        for (int rt = 0; rt < 4; ++rt) {
            v8h ap;
            {
                v4h a0 = *(const v4h*)(&sm.m.P_buf[pb][rt][lr][lkg*8]);
                v4h a1 = *(const v4h*)(&sm.m.P_buf[pb][rt][lr][lkg*8 + 4]);
                ap = __builtin_shufflevector(a0, a1, 0,1,2,3,4,5,6,7);
            }
            #pragma unroll
            for (int ct = 0; ct < 4; ++ct)
                acc_y[rt][ct] = __builtin_amdgcn_mfma_f32_16x16x32_f16(ap, gcur[ct], acc_y[rt][ct], 0, 0, 0);
        }
        __builtin_amdgcn_s_setprio(0);
    }

    // ---- epilogue 1: row sums, normalize Y into LDS (union overlay; all P_buf
    // reads finished before the barrier below; all gload_lds drained at t=30) ----
    lsum += __shfl_xor(lsum, 16);
    lsum += __shfl_xor(lsum, 32);
    if (lane < 16) smem_l[w*16 + lr] = lsum;
    __syncthreads();
    #pragma unroll
    for (int rt = 0; rt < 4; ++rt) {
        #pragma unroll
        for (int r = 0; r < 4; ++r) {
            int row = rt*16 + lkg*4 + r;
            float inv = 1.f / smem_l[row];
            #pragma unroll
            for (int ct = 0; ct < 4; ++ct)
                sm.Y[row][w*64 + ct*16 + lr] = (HF)(acc_y[rt][ct][r] * inv);
        }
    }
    __syncthreads();

    // ---- epilogue 2: out[co][n] = (wo @ Y^T) * scale + shift + x, co-slab per wave ----
    const HF* wob = wo + (long)(w*128)*CI;   // my 128 co rows
    v4f acc2[8][4];
    #pragma unroll
    for (int i = 0; i < 8; ++i)
        #pragma unroll
        for (int j = 0; j < 4; ++j) { v4f z = {0.f,0.f,0.f,0.f}; acc2[i][j] = z; }
    #pragma unroll
    for (int kf = 0; kf < 8; ++kf) {
        v8h bf2[4];
        #pragma unroll
        for (int nt = 0; nt < 4; ++nt)
            bf2[nt] = *(const v8h*)(&sm.Y[nt*16 + lr][kf*32 + lkg*8]);
        #pragma unroll
        for (int cot = 0; cot < 8; ++cot) {
            v8h af2 = *(const v8h*)(wob + (long)(cot*16 + lr)*CI + kf*32 + lkg*8);
            #pragma unroll
            for (int nt = 0; nt < 4; ++nt)
                acc2[cot][nt] = __builtin_amdgcn_mfma_f32_16x16x32_f16(af2, bf2[nt], acc2[cot][nt], 0, 0, 0);
        }
    }
    const float* xb = x + (long)b*Cc*HW + nbase;
    float* ob = out + (long)b*Cc*HW + nbase;
    #pragma unroll
    for (int cot = 0; cot < 8; ++cot) {
        int co = w*128 + cot*16 + lkg*4;
        #pragma unroll
        for (int r = 0; r < 4; ++r) {
            float sc = scale[co + r], sh = shift[co + r];
            #pragma unroll
            for (int nt = 0; nt < 4; ++nt) {
                long o = (long)(co + r)*HW + nt*16 + lr;
                ob[o] = acc2[cot][nt][r] * sc + sh + xb[o];
            }
        }
    }
}

extern "C" void kernel_launch(void* const* d_in, const int* in_sizes, int n_in,
                              void* d_out, int out_size, void* d_ws, size_t ws_size,
                              hipStream_t stream)
{
    const float* x     = (const float*)d_in[0];
    const float* w_g   = (const float*)d_in[1];
    const float* b_g   = (const float*)d_in[2];
    const float* w_th  = (const float*)d_in[3];
    const float* b_th  = (const float*)d_in[4];
    const float* w_ph  = (const float*)d_in[5];
    const float* b_ph  = (const float*)d_in[6];
    const float* w_out = (const float*)d_in[7];
    const float* b_out = (const float*)d_in[8];
    const float* gamma = (const float*)d_in[9];
    const float* beta  = (const float*)d_in[10];
    const float* mean  = (const float*)d_in[11];
    const float* var   = (const float*)d_in[12];
    float* out = (float*)d_out;

    char* ws = (char*)d_ws;
    size_t off = 0;
    auto alloc = [&](size_t bytes) { void* p = ws + off; off += (bytes + 255) & ~(size_t)255; return p; };
    HF*    wall  = (HF*)alloc((size_t)768*512*2);   // rows: theta 0-255, phi 256-511, g 512-767
    float* ball  = (float*)alloc(768*4);
    HF*    wo    = (HF*)alloc((size_t)512*256*2);
    float* scale = (float*)alloc(512*4);
    float* shift = (float*)alloc(512*4);
    HF*    xT    = (HF*)alloc((size_t)Bn*HW*Cc*2);
    HF*    TP    = (HF*)alloc((size_t)Bn*HW*512*2);  // [s][theta|phi] (phi half unused)
    HF*    Pt    = (HF*)alloc((size_t)Bn*Mp*CI*2);
    HF*    G     = (HF*)alloc((size_t)Bn*CI*Mp*2);

    prep_kernel<<<1536, 256, 0, stream>>>(w_g,b_g,w_th,b_th,w_ph,b_ph,w_out,b_out,gamma,beta,mean,var,
                                          wall, ball, wo, scale, shift);
    transpose_x_kernel<<<dim3(64,8,Bn), 256, 0, stream>>>(x, xT);
    // TP GEMM: theta written to TP; phi pooled in-epilogue -> Pt[m][c]
    gemm_bt_kernel<3><<<dim3(4,32,Bn), 256, 0, stream>>>(xT, (long)HW*Cc, wall, 0, TP, (long)HW*512,
                                                         HW, 512, Cc, ball, Pt);
    // Gg GEMM: C never materialized; pooled in-epilogue -> G[c][m]
    gemm_bt_kernel<4><<<dim3(32,2,Bn), 256, 0, stream>>>(wall + (size_t)512*512, 0, xT, (long)HW*Cc,
                                                         G, (long)CI*Mp, CI, HW, Cc, ball + 512, nullptr);
    // fused scores+softmax+PV+outconv+BN+residual -> out
    fused_attn_kernel<<<512, 256, 0, stream>>>(TP, Pt, G, wo, scale, shift, x, out);
}

// Round 23
// 180.524 us; speedup vs baseline: 1.7111x; 1.0245x over previous
//
#include <hip/hip_runtime.h>

typedef _Float16 v8h __attribute__((ext_vector_type(8)));
typedef _Float16 v4h __attribute__((ext_vector_type(4)));
typedef float v4f __attribute__((ext_vector_type(4)));
#define HF _Float16

// dims
#define Bn 8
#define Cc 512
#define CI 256
#define HW 4096   // 64*64
#define Mp 1024   // 32*32 pooled

__device__ __forceinline__ void gload16(const void* g, void* l) {
    __builtin_amdgcn_global_load_lds((const __attribute__((address_space(1))) void*)g,
                                     (__attribute__((address_space(3))) void*)l, 16, 0, 0);
}

// ---------------- prep: weights fp32->f16, BN fold ----------------
__global__ __launch_bounds__(256) void prep_kernel(
    const float* __restrict__ w_g, const float* __restrict__ b_g,
    const float* __restrict__ w_th, const float* __restrict__ b_th,
    const float* __restrict__ w_ph, const float* __restrict__ b_ph,
    const float* __restrict__ w_out, const float* __restrict__ b_out,
    const float* __restrict__ gamma, const float* __restrict__ beta,
    const float* __restrict__ mean, const float* __restrict__ var,
    HF* __restrict__ wall, float* __restrict__ ball,
    HF* __restrict__ wo, float* __restrict__ scale, float* __restrict__ shift)
{
    int idx = blockIdx.x * 256 + threadIdx.x;
    if (idx < 768*512) {
        int o = idx >> 9;
        float v = (o < 256) ? w_th[idx] : (o < 512) ? w_ph[idx - 256*512] : w_g[idx - 512*512];
        wall[idx] = (HF)v;
    }
    if (idx < 512*256) wo[idx] = (HF)w_out[idx];
    if (idx < 768) ball[idx] = (idx < 256) ? b_th[idx] : (idx < 512) ? b_ph[idx-256] : b_g[idx-512];
    if (idx < 512) {
        float inv = gamma[idx] * rsqrtf(var[idx] + 1e-5f);
        scale[idx] = inv;
        shift[idx] = (b_out[idx] - mean[idx]) * inv + beta[idx];
    }
}

// ---------------- transpose x: (b,c,s) fp32 -> xT (b,s,c) f16 ----------------
__global__ __launch_bounds__(256) void transpose_x_kernel(const float* __restrict__ x, HF* __restrict__ xT)
{
    __shared__ float tile[64][65];
    int b = blockIdx.z;
    int c0 = blockIdx.y * 64, s0 = blockIdx.x * 64;
    int tr = threadIdx.x >> 6, ts = threadIdx.x & 63;
    #pragma unroll
    for (int i = 0; i < 16; ++i) {
        int r = tr + i*4;
        tile[r][ts] = x[((long)(b*Cc) + c0 + r)*HW + s0 + ts];
    }
    __syncthreads();
    #pragma unroll
    for (int i = 0; i < 16; ++i) {
        int r = tr + i*4;
        xT[((long)b*HW + s0 + r)*Cc + c0 + ts] = (HF)tile[ts][r];
    }
}

// ---------------- gemm_bt with fused pool epilogues, XCD-pinned linear grid ----------
// C[i,j] = sum_k A[i,k]*B[j,k]. reg-staged, padded LDS, 2 barriers/step.
// Linear grid: b = bid&7 (all same-batch blocks on one XCD -> per-batch xT panel
// (4 MB) stays L2-resident); tile t = bid>>3, j0 fastest (NJS = log2(#j-tiles)).
// EPI 3 (TP):  theta cols (j0<256) -> C f16 = acc + colBias[j] to Cv.
//              phi cols (j0>=256) -> pool rows (s) 2x2 -> aux = Pt[m][c].
// EPI 4 (Gg):  pool cols (s) 2x2 -> Cv = G[c][m] ONLY (Gg never materialized).
template<int EPI, int NJS>
__global__ __launch_bounds__(256) void gemm_bt_kernel(
    const HF* __restrict__ A, long sA, const HF* __restrict__ B, long sB,
    void* __restrict__ Cv, long sC, int M, int N, int K,
    const float* __restrict__ bias, HF* __restrict__ aux)
{
    __shared__ union USm {
        struct { alignas(16) HF As[128][40]; alignas(16) HF Bs[128][40]; } s;
        alignas(16) HF Ct[128][132];   // epilogue pool buffer (As/Bs dead)
    } u;
    int bid = blockIdx.x;
    int b = bid & 7;
    int t = bid >> 3;
    int j0 = (t & ((1 << NJS) - 1)) * 128;
    int i0 = (t >> NJS) * 128;
    const HF* Ab = A + (long)b * sA;
    const HF* Bb = B + (long)b * sB;
    int tid = threadIdx.x;
    int lane = tid & 63, w = tid >> 6;
    int wr = w >> 1, wc = w & 1;
    int lr = lane & 15, lk = (lane >> 4) * 8;

    v4f acc[4][4];
    #pragma unroll
    for (int i = 0; i < 4; ++i)
        #pragma unroll
        for (int j = 0; j < 4; ++j) { v4f z = {0.f,0.f,0.f,0.f}; acc[i][j] = z; }

    for (int k0 = 0; k0 < K; k0 += 32) {
        #pragma unroll
        for (int q = 0; q < 2; ++q) {
            int ch = tid*2 + q;          // 0..511
            int row = ch >> 2;
            int c8 = (ch & 3) * 8;
            const uint4* ga = (const uint4*)(Ab + (long)(i0+row)*K + k0 + c8);
            *(uint4*)(&u.s.As[row][c8]) = *ga;
            const uint4* gb = (const uint4*)(Bb + (long)(j0+row)*K + k0 + c8);
            *(uint4*)(&u.s.Bs[row][c8]) = *gb;
        }
        __syncthreads();
        v8h af[4], bfr[4];
        #pragma unroll
        for (int mf = 0; mf < 4; ++mf)
            af[mf] = *(const v8h*)(&u.s.As[wr*64 + mf*16 + lr][lk]);
        #pragma unroll
        for (int nf = 0; nf < 4; ++nf)
            bfr[nf] = *(const v8h*)(&u.s.Bs[wc*64 + nf*16 + lr][lk]);
        #pragma unroll
        for (int mf = 0; mf < 4; ++mf)
            #pragma unroll
            for (int nf = 0; nf < 4; ++nf)
                acc[mf][nf] = __builtin_amdgcn_mfma_f32_16x16x32_f16(af[mf], bfr[nf], acc[mf][nf], 0, 0, 0);
        __syncthreads();
    }

    int rbase = (lane >> 4) * 4;
    bool pooled = (EPI == 4) || (EPI == 3 && j0 >= 256);
    #pragma unroll
    for (int mf = 0; mf < 4; ++mf) {
        #pragma unroll
        for (int nf = 0; nf < 4; ++nf) {
            #pragma unroll
            for (int r = 0; r < 4; ++r) {
                int rloc = wr*64 + mf*16 + rbase + r;
                int cloc = wc*64 + nf*16 + lr;
                float v = acc[mf][nf][r];
                if (EPI == 3) v += bias[j0 + cloc];        // colBias (o)
                else          v += bias[i0 + rloc];        // rowBias (c)
                if (pooled) {
                    u.Ct[rloc][cloc] = (HF)v;
                } else {  // EPI==3 theta: direct write
                    ((HF*)Cv + (long)b*sC)[(long)(i0 + rloc)*N + j0 + cloc] = (HF)v;
                }
            }
        }
    }

    if (pooled) {
        __syncthreads();
        if (EPI == 3) {
            // pool over ROWS (s): rows {2m,2m+1,64+2m,64+2m+1} -> Pt[m0+m][j0-256 + oc]
            int m = tid >> 3, oc = (tid & 7) * 16;
            int m0 = (i0 >> 7) * 32;
            HF* Pt_ = aux + (long)b*Mp*CI;
            HF res[16];
            #pragma unroll
            for (int j = 0; j < 16; ++j) {
                float v0 = fmaxf((float)u.Ct[2*m][oc+j],    (float)u.Ct[2*m+1][oc+j]);
                float v1 = fmaxf((float)u.Ct[64+2*m][oc+j], (float)u.Ct[64+2*m+1][oc+j]);
                res[j] = (HF)fmaxf(v0, v1);
            }
            HF* dst = Pt_ + (long)(m0 + m)*CI + (j0 - 256) + oc;
            *(v8h*)dst = *(v8h*)&res[0];
            *(v8h*)(dst + 8) = *(v8h*)&res[8];
        } else {
            // pool over COLS (s): G[i0+c][m0 + mg..mg+15]
            int c = tid >> 1, mg = (tid & 1) * 16;
            int m0 = (j0 >> 7) * 32;
            HF* Gp = (HF*)Cv + (long)b*sC;
            HF res[16];
            #pragma unroll
            for (int j = 0; j < 16; ++j) {
                int mm = mg + j;
                float v0 = fmaxf((float)u.Ct[c][2*mm],    (float)u.Ct[c][2*mm+1]);
                float v1 = fmaxf((float)u.Ct[c][64+2*mm], (float)u.Ct[c][64+2*mm+1]);
                res[j] = (HF)fmaxf(v0, v1);
            }
            HF* dst = Gp + (long)(i0 + c)*Mp + m0 + mg;
            *(v8h*)dst = *(v8h*)&res[0];
            *(v8h*)(dst + 8) = *(v8h*)&res[8];
        }
    }
}

// ---------------- fused flash attention (r18 configuration — measured optimum) ----------
// 512 blocks x 256 thr (4 waves), 2 blocks/CU. batch = bid&7 (XCD-pinned).
// Swapped QK^T, c-split PV, defer-rescale THR=7, G regs from L2 (1 iter ahead),
// P staged via gload_lds double-buffer; fused out-conv+BN+residual epilogue.
// Y_lds unioned over {P_lds, P_buf, smem_a} (epilogue-only).
__global__ __launch_bounds__(256, 2) void fused_attn_kernel(
    const HF* __restrict__ TP,   // [B][4096][512], theta = cols 0..255
    const HF* __restrict__ Pt,   // [B][1024][256]
    const HF* __restrict__ G,    // [B][256][1024]
    const HF* __restrict__ wo,   // [512][256]
    const float* __restrict__ scale, const float* __restrict__ shift,
    const float* __restrict__ x, // [B][512][4096] fp32
    float* __restrict__ out)     // [B][512][4096] fp32
{
    __shared__ union SMem {
        struct {
            alignas(16) HF P_lds[2][8192];      // [32 kg][32 row][8] k-group-major
            alignas(16) HF P_buf[2][4][16][36]; // [pb][rowgrp][n 16][m 32+4pad]
            alignas(16) float smem_a[2][4][16]; // [pb][rowgrp][n] alpha
        } m;
        alignas(16) HF Y[64][264];              // epilogue: normalized Y (row 528B)
    } sm;
    __shared__ float smem_l[64];                // final row sums

    int bid = blockIdx.x;
    int b = bid & 7;
    int ntile = bid >> 3;          // 0..63
    int tid = threadIdx.x;
    int lane = tid & 63, w = tid >> 6;
    int lr = lane & 15, lkg = lane >> 4;
    int nbase = ntile * 64;

    const HF* Tq = TP + ((long)b*HW + nbase + w*16) * 512;   // my 16 softmax rows
    const HF* Pb = Pt + (long)b*Mp*CI;
    const HF* Gb = G  + (long)b*CI*Mp + (long)(w*64)*Mp;     // my c-quadrant

    auto stage = [&](int bsel, int m0) {
        #pragma unroll
        for (int q = 0; q < 4; ++q) {
            int idxp = (w*4 + q)*64 + lane;         // 0..1023; dest = idxp*16B
            int pkg = idxp >> 5, prow = idxp & 31;  // [32 kg][32 row][8]
            gload16(Pb + (long)(m0 + prow)*CI + pkg*8, sm.m.P_lds[bsel] + (size_t)idxp*8);
        }
    };
    auto loadG = [&](int m0, v8h* g) {
        #pragma unroll
        for (int ct = 0; ct < 4; ++ct)
            g[ct] = *(const v8h*)(Gb + (long)(ct*16 + lr)*Mp + m0 + lkg*8);
    };

    // Q fragments in registers for whole kernel (theta cols of TP)
    v8h af[8];
    #pragma unroll
    for (int kf = 0; kf < 8; ++kf)
        af[kf] = *(const v8h*)(Tq + (long)lr*512 + kf*32 + lkg*8);

    v4f acc_y[4][4];   // [row-tile rt][c-tile ct]; Y row = rt*16+lkg*4+r, col = w*64+ct*16+lr
    #pragma unroll
    for (int i = 0; i < 4; ++i)
        #pragma unroll
        for (int j = 0; j < 4; ++j) { v4f z = {0.f,0.f,0.f,0.f}; acc_y[i][j] = z; }
    float mrun = -1e30f;   // running max for my row n = nbase + w*16 + lr
    float lsum = 0.f;      // per-lane partial sum over my m's

    v8h gA[4], gB[4];
    stage(0, 0);
    loadG(0, gA);
    __syncthreads();

    for (int t = 0; t < 32; ++t) {
        int cur = t & 1;
        int pb = t & 1;
        v8h* gcur  = (t & 1) ? gB : gA;
        v8h* gnext = (t & 1) ? gA : gB;
        if (t < 31) {
            stage(cur ^ 1, (t+1)*32);     // gload_lds next P chunk
            loadG((t+1)*32, gnext);       // G regs next chunk (issue-early)
        }

        // QK^T swapped: acc[mt] holds S[n=lr][m = mt*16 + lkg*4 + r]
        v4f acc[2];
        #pragma unroll
        for (int mt = 0; mt < 2; ++mt) { v4f z = {0.f,0.f,0.f,0.f}; acc[mt] = z; }
        __builtin_amdgcn_s_setprio(1);
        #pragma unroll
        for (int kf = 0; kf < 8; ++kf) {
            #pragma unroll
            for (int mt = 0; mt < 2; ++mt) {
                v8h pf = *(const v8h*)(sm.m.P_lds[cur] + (kf*4 + lkg)*256 + (mt*16 + lr)*8);
                acc[mt] = __builtin_amdgcn_mfma_f32_16x16x32_f16(pf, af[kf], acc[mt], 0, 0, 0);
            }
        }
        __builtin_amdgcn_s_setprio(0);

        // softmax: per-lane row n=lr. 7 in-lane max + 2 shuffles.
        float cm = fmaxf(fmaxf(fmaxf(acc[0][0], acc[0][1]), fmaxf(acc[0][2], acc[0][3])),
                         fmaxf(fmaxf(acc[1][0], acc[1][1]), fmaxf(acc[1][2], acc[1][3])));
        cm = fmaxf(cm, __shfl_xor(cm, 16));
        cm = fmaxf(cm, __shfl_xor(cm, 32));
        float alpha = 1.f;
        if (cm > mrun + 7.f) {            // defer: p <= e^7 = 1096, f16-safe
            alpha = __expf(mrun - cm);    // first iter: exp(-inf)=0 zeroes empty acc
            mrun = cm;
            lsum *= alpha;
        }
        if (lane < 16) sm.m.smem_a[pb][w][lr] = alpha;
        #pragma unroll
        for (int mt = 0; mt < 2; ++mt) {
            v4h p4;
            #pragma unroll
            for (int r = 0; r < 4; ++r) {
                float p = __expf(acc[mt][r] - mrun);
                lsum += p;
                p4[r] = (HF)p;
            }
            *(v4h*)(&sm.m.P_buf[pb][w][lr][mt*16 + lkg*4]) = p4;   // one b64 per mt
        }

        __syncthreads();   // P_buf[pb]+smem_a[pb] visible; vmcnt drained

        // PV: Y[64 n][my 64 c] += P(64x32) @ G^T (G in registers)
        __builtin_amdgcn_s_setprio(1);
        v4f alv[4];
        bool need = false;
        #pragma unroll
        for (int rt = 0; rt < 4; ++rt) {
            alv[rt] = *(const v4f*)(&sm.m.smem_a[pb][rt][lkg*4]);
            need = need | (alv[rt][0] != 1.f) | (alv[rt][1] != 1.f)
                        | (alv[rt][2] != 1.f) | (alv[rt][3] != 1.f);
        }
        if (__any(need)) {
            #pragma unroll
            for (int rt = 0; rt < 4; ++rt)
                #pragma unroll
                for (int ct = 0; ct < 4; ++ct)
                    #pragma unroll
                    for (int r = 0; r < 4; ++r)
                        acc_y[rt][ct][r] *= alv[rt][r];
        }
        #pragma unroll
        for (int rt = 0; rt < 4; ++rt) {
            v8h ap;
            {
                v4h a0 = *(const v4h*)(&sm.m.P_buf[pb][rt][lr][lkg*8]);
                v4h a1 = *(const v4h*)(&sm.m.P_buf[pb][rt][lr][lkg*8 + 4]);
                ap = __builtin_shufflevector(a0, a1, 0,1,2,3,4,5,6,7);
            }
            #pragma unroll
            for (int ct = 0; ct < 4; ++ct)
                acc_y[rt][ct] = __builtin_amdgcn_mfma_f32_16x16x32_f16(ap, gcur[ct], acc_y[rt][ct], 0, 0, 0);
        }
        __builtin_amdgcn_s_setprio(0);
    }

    // ---- epilogue 1: row sums, normalize Y into LDS (union overlay) ----
    lsum += __shfl_xor(lsum, 16);
    lsum += __shfl_xor(lsum, 32);
    if (lane < 16) smem_l[w*16 + lr] = lsum;
    __syncthreads();
    #pragma unroll
    for (int rt = 0; rt < 4; ++rt) {
        #pragma unroll
        for (int r = 0; r < 4; ++r) {
            int row = rt*16 + lkg*4 + r;
            float inv = 1.f / smem_l[row];
            #pragma unroll
            for (int ct = 0; ct < 4; ++ct)
                sm.Y[row][w*64 + ct*16 + lr] = (HF)(acc_y[rt][ct][r] * inv);
        }
    }
    __syncthreads();

    // ---- epilogue 2: out[co][n] = (wo @ Y^T) * scale + shift + x, co-slab per wave ----
    const HF* wob = wo + (long)(w*128)*CI;   // my 128 co rows
    v4f acc2[8][4];
    #pragma unroll
    for (int i = 0; i < 8; ++i)
        #pragma unroll
        for (int j = 0; j < 4; ++j) { v4f z = {0.f,0.f,0.f,0.f}; acc2[i][j] = z; }
    #pragma unroll
    for (int kf = 0; kf < 8; ++kf) {
        v8h bf2[4];
        #pragma unroll
        for (int nt = 0; nt < 4; ++nt)
            bf2[nt] = *(const v8h*)(&sm.Y[nt*16 + lr][kf*32 + lkg*8]);
        #pragma unroll
        for (int cot = 0; cot < 8; ++cot) {
            v8h af2 = *(const v8h*)(wob + (long)(cot*16 + lr)*CI + kf*32 + lkg*8);
            #pragma unroll
            for (int nt = 0; nt < 4; ++nt)
                acc2[cot][nt] = __builtin_amdgcn_mfma_f32_16x16x32_f16(af2, bf2[nt], acc2[cot][nt], 0, 0, 0);
        }
    }
    const float* xb = x + (long)b*Cc*HW + nbase;
    float* ob = out + (long)b*Cc*HW + nbase;
    #pragma unroll
    for (int cot = 0; cot < 8; ++cot) {
        int co = w*128 + cot*16 + lkg*4;
        #pragma unroll
        for (int r = 0; r < 4; ++r) {
            float sc = scale[co + r], sh = shift[co + r];
            #pragma unroll
            for (int nt = 0; nt < 4; ++nt) {
                long o = (long)(co + r)*HW + nt*16 + lr;
                ob[o] = acc2[cot][nt][r] * sc + sh + xb[o];
            }
        }
    }
}

extern "C" void kernel_launch(void* const* d_in, const int* in_sizes, int n_in,
                              void* d_out, int out_size, void* d_ws, size_t ws_size,
                              hipStream_t stream)
{
    const float* x     = (const float*)d_in[0];
    const float* w_g   = (const float*)d_in[1];
    const float* b_g   = (const float*)d_in[2];
    const float* w_th  = (const float*)d_in[3];
    const float* b_th  = (const float*)d_in[4];
    const float* w_ph  = (const float*)d_in[5];
    const float* b_ph  = (const float*)d_in[6];
    const float* w_out = (const float*)d_in[7];
    const float* b_out = (const float*)d_in[8];
    const float* gamma = (const float*)d_in[9];
    const float* beta  = (const float*)d_in[10];
    const float* mean  = (const float*)d_in[11];
    const float* var   = (const float*)d_in[12];
    float* out = (float*)d_out;

    char* ws = (char*)d_ws;
    size_t off = 0;
    auto alloc = [&](size_t bytes) { void* p = ws + off; off += (bytes + 255) & ~(size_t)255; return p; };
    HF*    wall  = (HF*)alloc((size_t)768*512*2);   // rows: theta 0-255, phi 256-511, g 512-767
    float* ball  = (float*)alloc(768*4);
    HF*    wo    = (HF*)alloc((size_t)512*256*2);
    float* scale = (float*)alloc(512*4);
    float* shift = (float*)alloc(512*4);
    HF*    xT    = (HF*)alloc((size_t)Bn*HW*Cc*2);
    HF*    TP    = (HF*)alloc((size_t)Bn*HW*512*2);  // [s][theta|phi] (phi half unused)
    HF*    Pt    = (HF*)alloc((size_t)Bn*Mp*CI*2);
    HF*    G     = (HF*)alloc((size_t)Bn*CI*Mp*2);

    prep_kernel<<<1536, 256, 0, stream>>>(w_g,b_g,w_th,b_th,w_ph,b_ph,w_out,b_out,gamma,beta,mean,var,
                                          wall, ball, wo, scale, shift);
    transpose_x_kernel<<<dim3(64,8,Bn), 256, 0, stream>>>(x, xT);
    // TP GEMM (XCD-pinned linear grid, 4 j-tiles x 32 i-tiles x 8 batches):
    // theta written to TP; phi pooled in-epilogue -> Pt[m][c]
    gemm_bt_kernel<3, 2><<<1024, 256, 0, stream>>>(xT, (long)HW*Cc, wall, 0, TP, (long)HW*512,
                                                   HW, 512, Cc, ball, Pt);
    // Gg GEMM (XCD-pinned, 32 j-tiles x 2 i-tiles x 8 batches):
    // C never materialized; pooled in-epilogue -> G[c][m]
    gemm_bt_kernel<4, 5><<<512, 256, 0, stream>>>(wall + (size_t)512*512, 0, xT, (long)HW*Cc,
                                                  G, (long)CI*Mp, CI, HW, Cc, ball + 512, nullptr);
    // fused scores+softmax+PV+outconv+BN+residual -> out
    fused_attn_kernel<<<512, 256, 0, stream>>>(TP, Pt, G, wo, scale, shift, x, out);
}